// Round 1
// baseline (593.195 us; speedup 1.0000x reference)
//
#include <hip/hip_runtime.h>
#include <math.h>

#define N0 4096
#define FDIM 500
#define H 256
#define KP1 3072
#define KP2 2304
#define KP3 1728
#define CAP 131072u

// ---------------- init ----------------
__global__ void init_kernel(float* racc, unsigned* dmax, unsigned* ecnt) {
  int t = threadIdx.x;
  if (t < 512) racc[t] = 0.f;
  if (t == 0) *dmax = 0u;
  if (t < 4) ecnt[t] = 0u;
}

// ---------------- row squared norms ----------------
__global__ void sq_kernel(const float* __restrict__ X, float* __restrict__ sq) {
  int row = blockIdx.x, lane = threadIdx.x;
  float s = 0.f;
  for (int k = lane; k < FDIM; k += 64) { float x = X[(size_t)row * FDIM + k]; s += x * x; }
  for (int off = 32; off; off >>= 1) s += __shfl_down(s, off);
  if (lane == 0) sq[row] = s;
}

// ---------------- distance tiles: pass0 = tile min + global max; pass1 = edge extraction ----------------
template<int PASS>
__global__ __launch_bounds__(256) void dist_kernel(
    const float* __restrict__ X, const float* __restrict__ sq,
    float* __restrict__ tmin, unsigned* __restrict__ dmax,
    uint2* __restrict__ edges, unsigned* __restrict__ ecnt) {
  const int bj = blockIdx.x, bi = blockIdx.y;
  if (bi < bj) return;
  float thr = 0.f;
  if (PASS == 1) {
    thr = 0.5f * __uint_as_float(*dmax);
    if (tmin[bi * 64 + bj] >= thr) return;  // tile provably has no edges (same math both passes)
  }
  __shared__ float As[16][68];
  __shared__ float Bs[16][68];
  const int tid = threadIdx.x;
  const int tx = tid & 15, ty = tid >> 4;
  const int lk = tid & 15, lr = tid >> 4;
  float acc[4][4] = {};
  for (int k0 = 0; k0 < FDIM; k0 += 16) {
#pragma unroll
    for (int q = 0; q < 4; ++q) {
      int r = lr + q * 16;
      int gk = k0 + lk;
      float av = 0.f, bv = 0.f;
      if (gk < FDIM) {
        av = X[(size_t)(bi * 64 + r) * FDIM + gk];
        bv = X[(size_t)(bj * 64 + r) * FDIM + gk];
      }
      As[lk][r] = av;
      Bs[lk][r] = bv;
    }
    __syncthreads();
#pragma unroll
    for (int kk = 0; kk < 16; ++kk) {
      const float4 a4 = *(const float4*)&As[kk][ty * 4];
      const float4 b4 = *(const float4*)&Bs[kk][tx * 4];
      const float av[4] = {a4.x, a4.y, a4.z, a4.w};
      const float bv[4] = {b4.x, b4.y, b4.z, b4.w};
#pragma unroll
      for (int i = 0; i < 4; ++i)
#pragma unroll
        for (int j = 0; j < 4; ++j) acc[i][j] += av[i] * bv[j];
    }
    __syncthreads();
  }
  if (PASS == 0) {
    float lmin = INFINITY, lmax = -INFINITY;
#pragma unroll
    for (int i = 0; i < 4; ++i) {
      int gi = bi * 64 + ty * 4 + i;
#pragma unroll
      for (int j = 0; j < 4; ++j) {
        int gj = bj * 64 + tx * 4 + j;
        if (gi > gj) {
          float Dv = sq[gi] + sq[gj] - 2.f * acc[i][j];
          lmin = fminf(lmin, Dv);
          lmax = fmaxf(lmax, Dv);
        }
      }
    }
    __syncthreads();
    float* red = &As[0][0];
    red[tid] = lmin;
    red[256 + tid] = lmax;
    __syncthreads();
    for (int s = 128; s > 0; s >>= 1) {
      if (tid < s) {
        red[tid] = fminf(red[tid], red[tid + s]);
        red[256 + tid] = fmaxf(red[256 + tid], red[256 + tid + s]);
      }
      __syncthreads();
    }
    if (tid == 0) {
      tmin[bi * 64 + bj] = red[0];
      float bmax = red[256];
      if (bmax > 0.f) atomicMax(dmax, __float_as_uint(bmax));  // positive floats: uint order == float order
    }
  } else {
#pragma unroll
    for (int i = 0; i < 4; ++i) {
      int gi = bi * 64 + ty * 4 + i;
#pragma unroll
      for (int j = 0; j < 4; ++j) {
        int gj = bj * 64 + tx * 4 + j;
        if (gi > gj) {
          float Dv = sq[gi] + sq[gj] - 2.f * acc[i][j];
          if (Dv < thr) {
            unsigned p = atomicAdd(ecnt, 1u);
            if (p < CAP) edges[p] = make_uint2((unsigned)gi, (unsigned)gj);  // (target, source), target > source
          }
        }
      }
    }
  }
}

// ---------------- dense GEMM: C[n x 256] = X[n x K] @ W[K x 256] (row stride of X == K) ----------------
__global__ __launch_bounds__(256) void xw_kernel(
    const float* __restrict__ X, const float* __restrict__ W, float* __restrict__ C, int K) {
  const int bc = blockIdx.x;  // 0..3 column block
  const int bi = blockIdx.y;
  __shared__ float As[16][68];
  __shared__ float Bs[16][68];
  const int tid = threadIdx.x;
  const int tx = tid & 15, ty = tid >> 4;
  float acc[4][4] = {};
  for (int k0 = 0; k0 < K; k0 += 16) {
    {
      int lk = tid & 15, lr = tid >> 4;
#pragma unroll
      for (int q = 0; q < 4; ++q) {
        int r = lr + q * 16, gk = k0 + lk;
        As[lk][r] = (gk < K) ? X[(size_t)(bi * 64 + r) * K + gk] : 0.f;
      }
      int c = tid & 63, kq = tid >> 6;
#pragma unroll
      for (int q = 0; q < 4; ++q) {
        int kk = kq + q * 4, gk = k0 + kk;
        Bs[kk][c] = (gk < K) ? W[(size_t)gk * H + bc * 64 + c] : 0.f;
      }
    }
    __syncthreads();
#pragma unroll
    for (int kk = 0; kk < 16; ++kk) {
      const float4 a4 = *(const float4*)&As[kk][ty * 4];
      const float4 b4 = *(const float4*)&Bs[kk][tx * 4];
      const float av[4] = {a4.x, a4.y, a4.z, a4.w};
      const float bv[4] = {b4.x, b4.y, b4.z, b4.w};
#pragma unroll
      for (int i = 0; i < 4; ++i)
#pragma unroll
        for (int j = 0; j < 4; ++j) acc[i][j] += av[i] * bv[j];
    }
    __syncthreads();
  }
#pragma unroll
  for (int i = 0; i < 4; ++i) {
    int gr = bi * 64 + ty * 4 + i;
#pragma unroll
    for (int j = 0; j < 4; ++j) C[(size_t)gr * H + bc * 64 + tx * 4 + j] = acc[i][j];
  }
}

// ---------------- small helpers ----------------
__global__ void fill_kernel(float* p, float val, int n) {
  int i = blockIdx.x * 256 + threadIdx.x;
  if (i < n) p[i] = val;
}
__global__ void deg_edge_kernel(const uint2* edges, const unsigned* ecnt, float* deg) {
  unsigned c = *ecnt; if (c > CAP) c = CAP;
  for (unsigned e = blockIdx.x * 256 + threadIdx.x; e < c; e += gridDim.x * 256)
    atomicAdd(&deg[edges[e].x], 1.f);
}
__global__ void rsqrt_kernel(float* d, const float* deg, int n) {
  int i = blockIdx.x * 256 + threadIdx.x;
  if (i < n) d[i] = rsqrtf(deg[i]);
}
__global__ void gcn_base_kernel(const float* __restrict__ xW, const float* __restrict__ dinv, float* __restrict__ tmp) {
  int i = blockIdx.x, h = threadIdx.x;
  float di = dinv[i];
  tmp[(size_t)i * H + h] = di * di * xW[(size_t)i * H + h];
}
__global__ void gcn_edge_kernel(const uint2* edges, const unsigned* ecnt,
                                const float* __restrict__ xW, const float* __restrict__ dinv, float* tmp) {
  unsigned c = *ecnt; if (c > CAP) c = CAP;
  int h = threadIdx.x;
  for (unsigned e = blockIdx.x; e < c; e += gridDim.x) {
    uint2 ed = edges[e];
    float w = dinv[ed.x] * dinv[ed.y];
    atomicAdd(&tmp[(size_t)ed.x * H + h], w * xW[(size_t)ed.y * H + h]);
  }
}
__global__ void relu_bias_kernel(const float* __restrict__ tmp, const float* __restrict__ b, float* __restrict__ y) {
  int i = blockIdx.x, h = threadIdx.x;
  y[(size_t)i * H + h] = fmaxf(tmp[(size_t)i * H + h] + b[h], 0.f);
}
// per-node u = y.Wr, v = y.Ws; also zero sagg
__global__ void uv_kernel(const float* __restrict__ y, const float* __restrict__ Wr,
                          const float* __restrict__ Ws, float* u, float* v, float* sagg) {
  int node = blockIdx.x, lane = threadIdx.x;  // 64 lanes
  float4 a = ((const float4*)(y + (size_t)node * H))[lane];
  float4 wr = ((const float4*)Wr)[lane];
  float4 ws = ((const float4*)Ws)[lane];
  float du = a.x * wr.x + a.y * wr.y + a.z * wr.z + a.w * wr.w;
  float dv = a.x * ws.x + a.y * ws.y + a.z * ws.z + a.w * ws.w;
  for (int off = 32; off; off >>= 1) { du += __shfl_down(du, off); dv += __shfl_down(dv, off); }
  if (lane == 0) { u[node] = du; v[node] = dv; sagg[node] = 0.f; }
}
__global__ void score_edge_kernel(const uint2* edges, const unsigned* ecnt, const float* u, float* sagg) {
  unsigned c = *ecnt; if (c > CAP) c = CAP;
  for (unsigned e = blockIdx.x * 256 + threadIdx.x; e < c; e += gridDim.x * 256) {
    uint2 ed = edges[e];
    atomicAdd(&sagg[ed.x], u[ed.y]);
  }
}
__global__ void score_kernel(const float* sagg, const float* v, const float* br, float* score, int n) {
  int i = blockIdx.x * 256 + threadIdx.x;
  if (i < n) score[i] = tanhf(sagg[i] + br[0] + v[i]);
}

// ---------------- top-k: single-block bitonic sort of 4096 packed keys ----------------
__global__ __launch_bounds__(1024) void topk_kernel(const float* __restrict__ score, int n, int k,
                                                    int* perm, int* newid, unsigned* nextcnt) {
  __shared__ unsigned long long keys[4096];
  int tid = threadIdx.x;
  for (int i = tid; i < 4096; i += 1024) {
    float s = (i < n) ? score[i] : -INFINITY;
    unsigned b = __float_as_uint(s);
    unsigned sortable = b ^ ((b & 0x80000000u) ? 0xFFFFFFFFu : 0x80000000u);  // order-preserving map
    keys[i] = ((unsigned long long)(~sortable) << 32) | (unsigned)i;          // ascending => score desc, idx asc
  }
  __syncthreads();
  for (int kk = 2; kk <= 4096; kk <<= 1) {
    for (int j = kk >> 1; j > 0; j >>= 1) {
      for (int i = tid; i < 4096; i += 1024) {
        int l = i ^ j;
        if (l > i) {
          unsigned long long a = keys[i], c = keys[l];
          bool up = ((i & kk) == 0);
          if ((a > c) == up) { keys[i] = c; keys[l] = a; }
        }
      }
      __syncthreads();
    }
  }
  for (int r = tid; r < 4096; r += 1024) {
    if (r < n) {
      int old = (int)(keys[r] & 0xFFFFFFFFu);
      newid[old] = (r < k) ? r : -1;
      if (r < k) perm[r] = old;
    }
  }
  if (tid == 0 && nextcnt) *nextcnt = 0u;
}

__global__ void gather_kernel(const float* __restrict__ y, const int* __restrict__ perm,
                              const float* __restrict__ score, float* __restrict__ xs) {
  int r = blockIdx.x, h = threadIdx.x;
  int old = perm[r];
  xs[(size_t)r * H + h] = y[(size_t)old * H + h] * score[old];
}
__global__ void filter_kernel(const uint2* in, const unsigned* incnt, const int* __restrict__ newid,
                              uint2* out, unsigned* outcnt) {
  unsigned c = *incnt; if (c > CAP) c = CAP;
  unsigned e = blockIdx.x * 256 + threadIdx.x;
  if (e < c) {
    uint2 ed = in[e];
    int nt = newid[ed.x], ns = newid[ed.y];
    if (nt >= 0 && ns >= 0) {
      unsigned p = atomicAdd(outcnt, 1u);
      if (p < CAP) out[p] = make_uint2((unsigned)nt, (unsigned)ns);
    }
  }
}

// ---------------- readout (col max + mean), 2-stage ----------------
__global__ void readout_part(const float* __restrict__ xs, int k, float* pmax, float* psum) {
  int h = threadIdx.x, b = blockIdx.x;  // 32 blocks x 256 threads
  float m = -INFINITY, s = 0.f;
  for (int r = b; r < k; r += 32) {
    float v = xs[(size_t)r * H + h];
    m = fmaxf(m, v);
    s += v;
  }
  pmax[b * H + h] = m;
  psum[b * H + h] = s;
}
__global__ void readout_fin(const float* pmax, const float* psum, float* racc, float invk) {
  int h = threadIdx.x;
  float m = -INFINITY, s = 0.f;
  for (int b = 0; b < 32; ++b) { m = fmaxf(m, pmax[b * H + h]); s += psum[b * H + h]; }
  racc[h] += m;
  racc[H + h] += s * invk;
}
__global__ void final_kernel(const float* racc, float* out) {
  int t = blockIdx.x * 256 + threadIdx.x;
  if (t < 512) out[t] = racc[t];
}

extern "C" void kernel_launch(void* const* d_in, const int* in_sizes, int n_in,
                              void* d_out, int out_size, void* d_ws, size_t ws_size,
                              hipStream_t stream) {
  const float* feat = (const float*)d_in[0];
  const float* W1 = (const float*)d_in[1];  const float* b1 = (const float*)d_in[2];
  const float* W2 = (const float*)d_in[3];  const float* b2 = (const float*)d_in[4];
  const float* W3 = (const float*)d_in[5];  const float* b3 = (const float*)d_in[6];
  const float* Wr1 = (const float*)d_in[7]; const float* br1 = (const float*)d_in[8]; const float* Ws1 = (const float*)d_in[9];
  const float* Wr2 = (const float*)d_in[10]; const float* br2 = (const float*)d_in[11]; const float* Ws2 = (const float*)d_in[12];
  const float* Wr3 = (const float*)d_in[13]; const float* br3 = (const float*)d_in[14]; const float* Ws3 = (const float*)d_in[15];
  float* out = (float*)d_out;

  char* w = (char*)d_ws;
  size_t o = 0;
  auto alloc = [&](size_t bytes) { size_t cur = o; o += (bytes + 255) & ~(size_t)255; return cur; };
  float* racc  = (float*)(w + alloc(512 * 4));
  unsigned* dmax = (unsigned*)(w + alloc(4));
  unsigned* ecnt = (unsigned*)(w + alloc(4 * 4));  // [0]=orig,[1]=after p1,[2]=after p2,[3]=unused
  float* sq    = (float*)(w + alloc(N0 * 4));
  float* tmin  = (float*)(w + alloc(4096 * 4));
  float* deg   = (float*)(w + alloc(N0 * 4));
  float* dinv  = (float*)(w + alloc(N0 * 4));
  float* u     = (float*)(w + alloc(N0 * 4));
  float* v     = (float*)(w + alloc(N0 * 4));
  float* sagg  = (float*)(w + alloc(N0 * 4));
  float* score = (float*)(w + alloc(N0 * 4));
  int* perm    = (int*)(w + alloc(N0 * 4));
  int* newid   = (int*)(w + alloc(N0 * 4));
  float* pmax  = (float*)(w + alloc(32 * H * 4));
  float* psum  = (float*)(w + alloc(32 * H * 4));
  uint2* edgesA = (uint2*)(w + alloc(CAP * 8));
  uint2* edgesB = (uint2*)(w + alloc(CAP * 8));
  float* xW = (float*)(w + alloc((size_t)N0 * H * 4));
  float* tmp = (float*)(w + alloc((size_t)N0 * H * 4));
  float* yA = (float*)(w + alloc((size_t)N0 * H * 4));
  float* yB = (float*)(w + alloc((size_t)N0 * H * 4));

  init_kernel<<<1, 512, 0, stream>>>(racc, dmax, ecnt);
  sq_kernel<<<N0, 64, 0, stream>>>(feat, sq);
  dim3 dgrid(64, 64);
  dist_kernel<0><<<dgrid, 256, 0, stream>>>(feat, sq, tmin, dmax, edgesA, ecnt);
  dist_kernel<1><<<dgrid, 256, 0, stream>>>(feat, sq, tmin, dmax, edgesA, ecnt);

  // ---- layer 1: n=N0, edges=edgesA(ecnt0) -> pooled k=KP1, edgesB(ecnt1)
  xw_kernel<<<dim3(4, N0 / 64), 256, 0, stream>>>(feat, W1, xW, FDIM);
  fill_kernel<<<(N0 + 255) / 256, 256, 0, stream>>>(deg, 1.f, N0);
  deg_edge_kernel<<<64, 256, 0, stream>>>(edgesA, &ecnt[0], deg);
  rsqrt_kernel<<<(N0 + 255) / 256, 256, 0, stream>>>(dinv, deg, N0);
  gcn_base_kernel<<<N0, 256, 0, stream>>>(xW, dinv, tmp);
  gcn_edge_kernel<<<256, 256, 0, stream>>>(edgesA, &ecnt[0], xW, dinv, tmp);
  relu_bias_kernel<<<N0, 256, 0, stream>>>(tmp, b1, yA);
  uv_kernel<<<N0, 64, 0, stream>>>(yA, Wr1, Ws1, u, v, sagg);
  score_edge_kernel<<<64, 256, 0, stream>>>(edgesA, &ecnt[0], u, sagg);
  score_kernel<<<(N0 + 255) / 256, 256, 0, stream>>>(sagg, v, br1, score, N0);
  topk_kernel<<<1, 1024, 0, stream>>>(score, N0, KP1, perm, newid, &ecnt[1]);
  gather_kernel<<<KP1, 256, 0, stream>>>(yA, perm, score, yB);
  filter_kernel<<<CAP / 256, 256, 0, stream>>>(edgesA, &ecnt[0], newid, edgesB, &ecnt[1]);
  readout_part<<<32, 256, 0, stream>>>(yB, KP1, pmax, psum);
  readout_fin<<<1, 256, 0, stream>>>(pmax, psum, racc, 1.f / KP1);

  // ---- layer 2: n=KP1, edges=edgesB(ecnt1) -> pooled k=KP2, edgesA(ecnt2)
  xw_kernel<<<dim3(4, KP1 / 64), 256, 0, stream>>>(yB, W2, xW, H);
  fill_kernel<<<(KP1 + 255) / 256, 256, 0, stream>>>(deg, 1.f, KP1);
  deg_edge_kernel<<<64, 256, 0, stream>>>(edgesB, &ecnt[1], deg);
  rsqrt_kernel<<<(KP1 + 255) / 256, 256, 0, stream>>>(dinv, deg, KP1);
  gcn_base_kernel<<<KP1, 256, 0, stream>>>(xW, dinv, tmp);
  gcn_edge_kernel<<<256, 256, 0, stream>>>(edgesB, &ecnt[1], xW, dinv, tmp);
  relu_bias_kernel<<<KP1, 256, 0, stream>>>(tmp, b2, yA);
  uv_kernel<<<KP1, 64, 0, stream>>>(yA, Wr2, Ws2, u, v, sagg);
  score_edge_kernel<<<64, 256, 0, stream>>>(edgesB, &ecnt[1], u, sagg);
  score_kernel<<<(KP1 + 255) / 256, 256, 0, stream>>>(sagg, v, br2, score, KP1);
  topk_kernel<<<1, 1024, 0, stream>>>(score, KP1, KP2, perm, newid, &ecnt[2]);
  gather_kernel<<<KP2, 256, 0, stream>>>(yA, perm, score, yB);
  filter_kernel<<<CAP / 256, 256, 0, stream>>>(edgesB, &ecnt[1], newid, edgesA, &ecnt[2]);
  readout_part<<<32, 256, 0, stream>>>(yB, KP2, pmax, psum);
  readout_fin<<<1, 256, 0, stream>>>(pmax, psum, racc, 1.f / KP2);

  // ---- layer 3: n=KP2, edges=edgesA(ecnt2) -> pooled k=KP3 (no further edge filter needed)
  xw_kernel<<<dim3(4, KP2 / 64), 256, 0, stream>>>(yB, W3, xW, H);
  fill_kernel<<<(KP2 + 255) / 256, 256, 0, stream>>>(deg, 1.f, KP2);
  deg_edge_kernel<<<64, 256, 0, stream>>>(edgesA, &ecnt[2], deg);
  rsqrt_kernel<<<(KP2 + 255) / 256, 256, 0, stream>>>(dinv, deg, KP2);
  gcn_base_kernel<<<KP2, 256, 0, stream>>>(xW, dinv, tmp);
  gcn_edge_kernel<<<256, 256, 0, stream>>>(edgesA, &ecnt[2], xW, dinv, tmp);
  relu_bias_kernel<<<KP2, 256, 0, stream>>>(tmp, b3, yA);
  uv_kernel<<<KP2, 64, 0, stream>>>(yA, Wr3, Ws3, u, v, sagg);
  score_edge_kernel<<<64, 256, 0, stream>>>(edgesA, &ecnt[2], u, sagg);
  score_kernel<<<(KP2 + 255) / 256, 256, 0, stream>>>(sagg, v, br3, score, KP2);
  topk_kernel<<<1, 1024, 0, stream>>>(score, KP2, KP3, perm, newid, &ecnt[3]);
  gather_kernel<<<KP3, 256, 0, stream>>>(yA, perm, score, yB);
  readout_part<<<32, 256, 0, stream>>>(yB, KP3, pmax, psum);
  readout_fin<<<1, 256, 0, stream>>>(pmax, psum, racc, 1.f / KP3);

  final_kernel<<<2, 256, 0, stream>>>(racc, out);
}

// Round 2
// 493.113 us; speedup vs baseline: 1.2030x; 1.2030x over previous
//
#include <hip/hip_runtime.h>
#include <math.h>

#define N0 4096
#define FDIM 500
#define H 256
#define KP1 3072
#define KP2 2304
#define KP3 1728
#define CAP 131072u
#define KPAD 512

typedef __attribute__((ext_vector_type(8))) short bf16x8;
typedef __attribute__((ext_vector_type(4))) float f32x4;

__device__ inline unsigned short f2bf(float x) {
  unsigned u = __float_as_uint(x);
  unsigned r = (u + 0x7fffu + ((u >> 16) & 1u)) >> 16;
  return (unsigned short)r;
}
__device__ inline float bf2f(unsigned short h) { return __uint_as_float(((unsigned)h) << 16); }

// ---------------- init ----------------
__global__ void init_kernel(float* racc, unsigned* dmax, unsigned* ecnt) {
  int t = threadIdx.x;
  if (t < 512) racc[t] = 0.f;
  if (t == 0) *dmax = 0u;
  if (t < 4) ecnt[t] = 0u;
}

// ---------------- row squared norms ----------------
__global__ void sq_kernel(const float* __restrict__ X, float* __restrict__ sq) {
  int row = blockIdx.x, lane = threadIdx.x;
  float s = 0.f;
  for (int k = lane; k < FDIM; k += 64) { float x = X[(size_t)row * FDIM + k]; s += x * x; }
  for (int off = 32; off; off >>= 1) s += __shfl_down(s, off);
  if (lane == 0) sq[row] = s;
}

// ---------------- split-bf16 conversion: feat -> Xh, Xm [4096][512] ----------------
__global__ void conv_kernel(const float* __restrict__ X, unsigned short* __restrict__ Xh,
                            unsigned short* __restrict__ Xm) {
  int i = blockIdx.x * 256 + threadIdx.x;  // over 4096*512
  int row = i >> 9, k = i & 511;
  float x = (k < FDIM) ? X[(size_t)row * FDIM + k] : 0.f;
  unsigned short h = f2bf(x);
  unsigned short m = f2bf(x - bf2f(h));
  Xh[i] = h;
  Xm[i] = m;
}

// ---------------- MFMA distance tiles (split-bf16 Gram), 128x128 tile, lower-tri grid ----------------
// PASS 0: per-tile min + global max (atomic). PASS 1: early-exit on tmin, else re-emit edges.
template<int PASS>
__global__ __launch_bounds__(256) void distm_kernel(
    const unsigned short* __restrict__ Xh, const unsigned short* __restrict__ Xm,
    const float* __restrict__ sq, float* __restrict__ tmin, unsigned* __restrict__ dmax,
    uint2* __restrict__ edges, unsigned* __restrict__ ecnt) {
  int t = blockIdx.x;
  int bi = (int)((sqrtf(8.f * (float)t + 1.f) - 1.f) * 0.5f);
  while ((bi + 1) * (bi + 2) / 2 <= t) ++bi;
  while (bi * (bi + 1) / 2 > t) --bi;
  int bj = t - bi * (bi + 1) / 2;  // bj <= bi

  float thr = 0.f;
  if (PASS == 1) {
    thr = 0.5f * __uint_as_float(*dmax);
    if (tmin[t] >= thr) return;
  }

  __shared__ unsigned short Lah[128 * 32];
  __shared__ unsigned short Lam[128 * 32];
  __shared__ unsigned short Lbh[128 * 32];
  __shared__ unsigned short Lbm[128 * 32];

  const int tid = threadIdx.x;
  const int lane = tid & 63;
  const int w = tid >> 6;          // wave 0..3
  const int wr = w >> 1, wc = w & 1;
  const int fr = lane & 15;        // frag row/col
  const int kg = lane >> 4;        // k-group 0..3

  const int Ibase = bi * 128, Jbase = bj * 128;

  f32x4 acc[4][4] = {};

  for (int k0 = 0; k0 < KPAD; k0 += 32) {
    // stage 4 tiles of [128][32] bf16 (8KB each)
#pragma unroll
    for (int s = 0; s < 2; ++s) {
      int eo = s * 2048 + tid * 8;
      int row = s * 64 + (tid >> 2);
      int kk = (tid & 3) * 8;
      size_t ga = (size_t)(Ibase + row) * KPAD + k0 + kk;
      size_t gb = (size_t)(Jbase + row) * KPAD + k0 + kk;
      *(bf16x8*)&Lah[eo] = *(const bf16x8*)&Xh[ga];
      *(bf16x8*)&Lam[eo] = *(const bf16x8*)&Xm[ga];
      *(bf16x8*)&Lbh[eo] = *(const bf16x8*)&Xh[gb];
      *(bf16x8*)&Lbm[eo] = *(const bf16x8*)&Xm[gb];
    }
    __syncthreads();
    bf16x8 ah[4], am[4], bh[4], bm[4];
#pragma unroll
    for (int f = 0; f < 4; ++f) {
      int ra = (wr * 64 + f * 16 + fr) * 32 + kg * 8;
      int rb = (wc * 64 + f * 16 + fr) * 32 + kg * 8;
      ah[f] = *(const bf16x8*)&Lah[ra];
      am[f] = *(const bf16x8*)&Lam[ra];
      bh[f] = *(const bf16x8*)&Lbh[rb];
      bm[f] = *(const bf16x8*)&Lbm[rb];
    }
#pragma unroll
    for (int i = 0; i < 4; ++i)
#pragma unroll
      for (int j = 0; j < 4; ++j) {
        acc[i][j] = __builtin_amdgcn_mfma_f32_16x16x32_bf16(ah[i], bh[j], acc[i][j], 0, 0, 0);
        acc[i][j] = __builtin_amdgcn_mfma_f32_16x16x32_bf16(ah[i], bm[j], acc[i][j], 0, 0, 0);
        acc[i][j] = __builtin_amdgcn_mfma_f32_16x16x32_bf16(am[i], bh[j], acc[i][j], 0, 0, 0);
      }
    __syncthreads();
  }

  // epilogue: D = sq[gi] + sq[gj] - 2*G, valid for gi > gj
  const int Ib = Ibase + wr * 64, Jb = Jbase + wc * 64;
  const int col = fr, rgrp = kg;  // C/D layout: col = lane&15, row = (lane>>4)*4 + reg

  float sqj[4];
#pragma unroll
  for (int j = 0; j < 4; ++j) sqj[j] = sq[Jb + j * 16 + col];

  if (PASS == 0) {
    float lmin = INFINITY, lmax = -INFINITY;
#pragma unroll
    for (int i = 0; i < 4; ++i)
#pragma unroll
      for (int r = 0; r < 4; ++r) {
        int gi = Ib + i * 16 + rgrp * 4 + r;
        float sqi = sq[gi];
#pragma unroll
        for (int j = 0; j < 4; ++j) {
          int gj = Jb + j * 16 + col;
          if (gi > gj) {
            float Dv = sqi + sqj[j] - 2.f * acc[i][j][r];
            lmin = fminf(lmin, Dv);
            lmax = fmaxf(lmax, Dv);
          }
        }
      }
    __syncthreads();
    float* red = (float*)Lah;
    red[tid] = lmin;
    red[256 + tid] = lmax;
    __syncthreads();
    for (int s2 = 128; s2 > 0; s2 >>= 1) {
      if (tid < s2) {
        red[tid] = fminf(red[tid], red[tid + s2]);
        red[256 + tid] = fmaxf(red[256 + tid], red[256 + tid + s2]);
      }
      __syncthreads();
    }
    if (tid == 0) {
      tmin[t] = red[0];
      float bmax = red[256];
      if (bmax > 0.f) atomicMax(dmax, __float_as_uint(bmax));  // positive floats: uint order == float order
    }
  } else {
#pragma unroll
    for (int i = 0; i < 4; ++i)
#pragma unroll
      for (int r = 0; r < 4; ++r) {
        int gi = Ib + i * 16 + rgrp * 4 + r;
        float sqi = sq[gi];
#pragma unroll
        for (int j = 0; j < 4; ++j) {
          int gj = Jb + j * 16 + col;
          if (gi > gj) {
            float Dv = sqi + sqj[j] - 2.f * acc[i][j][r];
            if (Dv < thr) {
              unsigned p = atomicAdd(ecnt, 1u);
              if (p < CAP) edges[p] = make_uint2((unsigned)gi, (unsigned)gj);  // (target, source)
            }
          }
        }
      }
  }
}

// ---------------- dense GEMM: C[n x 256] = X[n x K] @ W[K x 256] ----------------
__global__ __launch_bounds__(256) void xw_kernel(
    const float* __restrict__ X, const float* __restrict__ W, float* __restrict__ C, int K) {
  const int bc = blockIdx.x;  // 0..3 column block
  const int bi = blockIdx.y;
  __shared__ float As[16][68];
  __shared__ float Bs[16][68];
  const int tid = threadIdx.x;
  const int tx = tid & 15, ty = tid >> 4;
  float acc[4][4] = {};
  for (int k0 = 0; k0 < K; k0 += 16) {
    {
      int lk = tid & 15, lr = tid >> 4;
#pragma unroll
      for (int q = 0; q < 4; ++q) {
        int r = lr + q * 16, gk = k0 + lk;
        As[lk][r] = (gk < K) ? X[(size_t)(bi * 64 + r) * K + gk] : 0.f;
      }
      int c = tid & 63, kq = tid >> 6;
#pragma unroll
      for (int q = 0; q < 4; ++q) {
        int kk = kq + q * 4, gk = k0 + kk;
        Bs[kk][c] = (gk < K) ? W[(size_t)gk * H + bc * 64 + c] : 0.f;
      }
    }
    __syncthreads();
#pragma unroll
    for (int kk = 0; kk < 16; ++kk) {
      const float4 a4 = *(const float4*)&As[kk][ty * 4];
      const float4 b4 = *(const float4*)&Bs[kk][tx * 4];
      const float av[4] = {a4.x, a4.y, a4.z, a4.w};
      const float bv[4] = {b4.x, b4.y, b4.z, b4.w};
#pragma unroll
      for (int i = 0; i < 4; ++i)
#pragma unroll
        for (int j = 0; j < 4; ++j) acc[i][j] += av[i] * bv[j];
    }
    __syncthreads();
  }
#pragma unroll
  for (int i = 0; i < 4; ++i) {
    int gr = bi * 64 + ty * 4 + i;
#pragma unroll
    for (int j = 0; j < 4; ++j) C[(size_t)gr * H + bc * 64 + tx * 4 + j] = acc[i][j];
  }
}

// ---------------- small helpers ----------------
__global__ void fill_kernel(float* p, float val, int n) {
  int i = blockIdx.x * 256 + threadIdx.x;
  if (i < n) p[i] = val;
}
__global__ void deg_edge_kernel(const uint2* edges, const unsigned* ecnt, float* deg) {
  unsigned c = *ecnt; if (c > CAP) c = CAP;
  for (unsigned e = blockIdx.x * 256 + threadIdx.x; e < c; e += gridDim.x * 256)
    atomicAdd(&deg[edges[e].x], 1.f);
}
__global__ void rsqrt_kernel(float* d, const float* deg, int n) {
  int i = blockIdx.x * 256 + threadIdx.x;
  if (i < n) d[i] = rsqrtf(deg[i]);
}
__global__ void gcn_base_kernel(const float* __restrict__ xW, const float* __restrict__ dinv, float* __restrict__ tmp) {
  int i = blockIdx.x, h = threadIdx.x;
  float di = dinv[i];
  tmp[(size_t)i * H + h] = di * di * xW[(size_t)i * H + h];
}
__global__ void gcn_edge_kernel(const uint2* edges, const unsigned* ecnt,
                                const float* __restrict__ xW, const float* __restrict__ dinv, float* tmp) {
  unsigned c = *ecnt; if (c > CAP) c = CAP;
  int h = threadIdx.x;
  for (unsigned e = blockIdx.x; e < c; e += gridDim.x) {
    uint2 ed = edges[e];
    float wgt = dinv[ed.x] * dinv[ed.y];
    atomicAdd(&tmp[(size_t)ed.x * H + h], wgt * xW[(size_t)ed.y * H + h]);
  }
}
__global__ void relu_bias_kernel(const float* __restrict__ tmp, const float* __restrict__ b, float* __restrict__ y) {
  int i = blockIdx.x, h = threadIdx.x;
  y[(size_t)i * H + h] = fmaxf(tmp[(size_t)i * H + h] + b[h], 0.f);
}
__global__ void uv_kernel(const float* __restrict__ y, const float* __restrict__ Wr,
                          const float* __restrict__ Ws, float* u, float* v, float* sagg) {
  int node = blockIdx.x, lane = threadIdx.x;  // 64 lanes
  float4 a = ((const float4*)(y + (size_t)node * H))[lane];
  float4 wr = ((const float4*)Wr)[lane];
  float4 ws = ((const float4*)Ws)[lane];
  float du = a.x * wr.x + a.y * wr.y + a.z * wr.z + a.w * wr.w;
  float dv = a.x * ws.x + a.y * ws.y + a.z * ws.z + a.w * ws.w;
  for (int off = 32; off; off >>= 1) { du += __shfl_down(du, off); dv += __shfl_down(dv, off); }
  if (lane == 0) { u[node] = du; v[node] = dv; sagg[node] = 0.f; }
}
__global__ void score_edge_kernel(const uint2* edges, const unsigned* ecnt, const float* u, float* sagg) {
  unsigned c = *ecnt; if (c > CAP) c = CAP;
  for (unsigned e = blockIdx.x * 256 + threadIdx.x; e < c; e += gridDim.x * 256) {
    uint2 ed = edges[e];
    atomicAdd(&sagg[ed.x], u[ed.y]);
  }
}

// ---------------- top-k (score fused in): single-block bitonic sort of 4096 packed keys ----------------
__global__ __launch_bounds__(1024) void topk_kernel(const float* __restrict__ sagg, const float* __restrict__ v,
                                                    const float* __restrict__ br, float* __restrict__ score,
                                                    int n, int k, int* perm, int* newid, unsigned* nextcnt) {
  __shared__ unsigned long long keys[4096];
  int tid = threadIdx.x;
  float brv = br[0];
  for (int i = tid; i < 4096; i += 1024) {
    float s = -INFINITY;
    if (i < n) { s = tanhf(sagg[i] + brv + v[i]); score[i] = s; }
    unsigned b = __float_as_uint(s);
    unsigned sortable = b ^ ((b & 0x80000000u) ? 0xFFFFFFFFu : 0x80000000u);
    keys[i] = ((unsigned long long)(~sortable) << 32) | (unsigned)i;  // ascending => score desc, idx asc
  }
  __syncthreads();
  for (int kk = 2; kk <= 4096; kk <<= 1) {
    for (int j = kk >> 1; j > 0; j >>= 1) {
      for (int i = tid; i < 4096; i += 1024) {
        int l = i ^ j;
        if (l > i) {
          unsigned long long a = keys[i], c = keys[l];
          bool up = ((i & kk) == 0);
          if ((a > c) == up) { keys[i] = c; keys[l] = a; }
        }
      }
      __syncthreads();
    }
  }
  for (int r = tid; r < 4096; r += 1024) {
    if (r < n) {
      int old = (int)(keys[r] & 0xFFFFFFFFu);
      newid[old] = (r < k) ? r : -1;
      if (r < k) perm[r] = old;
    }
  }
  if (tid == 0 && nextcnt) *nextcnt = 0u;
}

__global__ void gather_kernel(const float* __restrict__ y, const int* __restrict__ perm,
                              const float* __restrict__ score, float* __restrict__ xs) {
  int r = blockIdx.x, h = threadIdx.x;
  int old = perm[r];
  xs[(size_t)r * H + h] = y[(size_t)old * H + h] * score[old];
}
__global__ void filter_kernel(const uint2* in, const unsigned* incnt, const int* __restrict__ newid,
                              uint2* out, unsigned* outcnt) {
  unsigned c = *incnt; if (c > CAP) c = CAP;
  unsigned e = blockIdx.x * 256 + threadIdx.x;
  if (e < c) {
    uint2 ed = in[e];
    int nt = newid[ed.x], ns = newid[ed.y];
    if (nt >= 0 && ns >= 0) {
      unsigned p = atomicAdd(outcnt, 1u);
      if (p < CAP) out[p] = make_uint2((unsigned)nt, (unsigned)ns);
    }
  }
}

// ---------------- readout (col max + mean), 2-stage ----------------
__global__ void readout_part(const float* __restrict__ xs, int k, float* pmax, float* psum) {
  int h = threadIdx.x, b = blockIdx.x;  // 32 blocks x 256 threads
  float m = -INFINITY, s = 0.f;
  for (int r = b; r < k; r += 32) {
    float vv = xs[(size_t)r * H + h];
    m = fmaxf(m, vv);
    s += vv;
  }
  pmax[b * H + h] = m;
  psum[b * H + h] = s;
}
__global__ void readout_fin(const float* pmax, const float* psum, float* racc, float invk) {
  int h = threadIdx.x;
  float m = -INFINITY, s = 0.f;
  for (int b = 0; b < 32; ++b) { m = fmaxf(m, pmax[b * H + h]); s += psum[b * H + h]; }
  racc[h] += m;
  racc[H + h] += s * invk;
}
__global__ void final_kernel(const float* racc, float* out) {
  int t = blockIdx.x * 256 + threadIdx.x;
  if (t < 512) out[t] = racc[t];
}

extern "C" void kernel_launch(void* const* d_in, const int* in_sizes, int n_in,
                              void* d_out, int out_size, void* d_ws, size_t ws_size,
                              hipStream_t stream) {
  const float* feat = (const float*)d_in[0];
  const float* W1 = (const float*)d_in[1];  const float* b1 = (const float*)d_in[2];
  const float* W2 = (const float*)d_in[3];  const float* b2 = (const float*)d_in[4];
  const float* W3 = (const float*)d_in[5];  const float* b3 = (const float*)d_in[6];
  const float* Wr1 = (const float*)d_in[7]; const float* br1 = (const float*)d_in[8]; const float* Ws1 = (const float*)d_in[9];
  const float* Wr2 = (const float*)d_in[10]; const float* br2 = (const float*)d_in[11]; const float* Ws2 = (const float*)d_in[12];
  const float* Wr3 = (const float*)d_in[13]; const float* br3 = (const float*)d_in[14]; const float* Ws3 = (const float*)d_in[15];
  float* out = (float*)d_out;

  char* w = (char*)d_ws;
  size_t o = 0;
  auto alloc = [&](size_t bytes) { size_t cur = o; o += (bytes + 255) & ~(size_t)255; return cur; };
  float* racc  = (float*)(w + alloc(512 * 4));
  unsigned* dmax = (unsigned*)(w + alloc(4));
  unsigned* ecnt = (unsigned*)(w + alloc(4 * 4));
  float* sq    = (float*)(w + alloc(N0 * 4));
  float* tmin  = (float*)(w + alloc(4096 * 4));
  float* deg   = (float*)(w + alloc(N0 * 4));
  float* dinv  = (float*)(w + alloc(N0 * 4));
  float* u     = (float*)(w + alloc(N0 * 4));
  float* v     = (float*)(w + alloc(N0 * 4));
  float* sagg  = (float*)(w + alloc(N0 * 4));
  float* score = (float*)(w + alloc(N0 * 4));
  int* perm    = (int*)(w + alloc(N0 * 4));
  int* newid   = (int*)(w + alloc(N0 * 4));
  float* pmax  = (float*)(w + alloc(32 * H * 4));
  float* psum  = (float*)(w + alloc(32 * H * 4));
  uint2* edgesA = (uint2*)(w + alloc(CAP * 8));
  uint2* edgesB = (uint2*)(w + alloc(CAP * 8));
  float* xW = (float*)(w + alloc((size_t)N0 * H * 4));
  float* tmp = (float*)(w + alloc((size_t)N0 * H * 4));
  float* yA = (float*)(w + alloc((size_t)N0 * H * 4));   // also Xh before layer1 relu
  float* yB = (float*)(w + alloc((size_t)N0 * H * 4));   // also Xm before layer1 gather

  // split-bf16 overlays (dist-only lifetime, before yA/yB are first written)
  unsigned short* Xh = (unsigned short*)yA;  // 4096*512*2 = 4MB
  unsigned short* Xm = (unsigned short*)yB;

  init_kernel<<<1, 512, 0, stream>>>(racc, dmax, ecnt);
  sq_kernel<<<N0, 64, 0, stream>>>(feat, sq);
  conv_kernel<<<(N0 * KPAD) / 256, 256, 0, stream>>>(feat, Xh, Xm);
  distm_kernel<0><<<528, 256, 0, stream>>>(Xh, Xm, sq, tmin, dmax, edgesA, ecnt);
  distm_kernel<1><<<528, 256, 0, stream>>>(Xh, Xm, sq, tmin, dmax, edgesA, ecnt);

  // ---- layer 1: n=N0, edges=edgesA(ecnt0) -> pooled k=KP1, edgesB(ecnt1)
  xw_kernel<<<dim3(4, N0 / 64), 256, 0, stream>>>(feat, W1, xW, FDIM);
  fill_kernel<<<(N0 + 255) / 256, 256, 0, stream>>>(deg, 1.f, N0);
  deg_edge_kernel<<<64, 256, 0, stream>>>(edgesA, &ecnt[0], deg);
  rsqrt_kernel<<<(N0 + 255) / 256, 256, 0, stream>>>(dinv, deg, N0);
  gcn_base_kernel<<<N0, 256, 0, stream>>>(xW, dinv, tmp);
  gcn_edge_kernel<<<256, 256, 0, stream>>>(edgesA, &ecnt[0], xW, dinv, tmp);
  relu_bias_kernel<<<N0, 256, 0, stream>>>(tmp, b1, yA);
  uv_kernel<<<N0, 64, 0, stream>>>(yA, Wr1, Ws1, u, v, sagg);
  score_edge_kernel<<<64, 256, 0, stream>>>(edgesA, &ecnt[0], u, sagg);
  topk_kernel<<<1, 1024, 0, stream>>>(sagg, v, br1, score, N0, KP1, perm, newid, &ecnt[1]);
  gather_kernel<<<KP1, 256, 0, stream>>>(yA, perm, score, yB);
  filter_kernel<<<CAP / 256, 256, 0, stream>>>(edgesA, &ecnt[0], newid, edgesB, &ecnt[1]);
  readout_part<<<32, 256, 0, stream>>>(yB, KP1, pmax, psum);
  readout_fin<<<1, 256, 0, stream>>>(pmax, psum, racc, 1.f / KP1);

  // ---- layer 2: n=KP1, edges=edgesB(ecnt1) -> pooled k=KP2, edgesA(ecnt2)
  xw_kernel<<<dim3(4, KP1 / 64), 256, 0, stream>>>(yB, W2, xW, H);
  fill_kernel<<<(KP1 + 255) / 256, 256, 0, stream>>>(deg, 1.f, KP1);
  deg_edge_kernel<<<64, 256, 0, stream>>>(edgesB, &ecnt[1], deg);
  rsqrt_kernel<<<(KP1 + 255) / 256, 256, 0, stream>>>(dinv, deg, KP1);
  gcn_base_kernel<<<KP1, 256, 0, stream>>>(xW, dinv, tmp);
  gcn_edge_kernel<<<256, 256, 0, stream>>>(edgesB, &ecnt[1], xW, dinv, tmp);
  relu_bias_kernel<<<KP1, 256, 0, stream>>>(tmp, b2, yA);
  uv_kernel<<<KP1, 64, 0, stream>>>(yA, Wr2, Ws2, u, v, sagg);
  score_edge_kernel<<<64, 256, 0, stream>>>(edgesB, &ecnt[1], u, sagg);
  topk_kernel<<<1, 1024, 0, stream>>>(sagg, v, br2, score, KP1, KP2, perm, newid, &ecnt[2]);
  gather_kernel<<<KP2, 256, 0, stream>>>(yA, perm, score, yB);
  filter_kernel<<<CAP / 256, 256, 0, stream>>>(edgesB, &ecnt[1], newid, edgesA, &ecnt[2]);
  readout_part<<<32, 256, 0, stream>>>(yB, KP2, pmax, psum);
  readout_fin<<<1, 256, 0, stream>>>(pmax, psum, racc, 1.f / KP2);

  // ---- layer 3: n=KP2, edges=edgesA(ecnt2) -> pooled k=KP3
  xw_kernel<<<dim3(4, KP2 / 64), 256, 0, stream>>>(yB, W3, xW, H);
  fill_kernel<<<(KP2 + 255) / 256, 256, 0, stream>>>(deg, 1.f, KP2);
  deg_edge_kernel<<<64, 256, 0, stream>>>(edgesA, &ecnt[2], deg);
  rsqrt_kernel<<<(KP2 + 255) / 256, 256, 0, stream>>>(dinv, deg, KP2);
  gcn_base_kernel<<<KP2, 256, 0, stream>>>(xW, dinv, tmp);
  gcn_edge_kernel<<<256, 256, 0, stream>>>(edgesA, &ecnt[2], xW, dinv, tmp);
  relu_bias_kernel<<<KP2, 256, 0, stream>>>(tmp, b3, yA);
  uv_kernel<<<KP2, 64, 0, stream>>>(yA, Wr3, Ws3, u, v, sagg);
  score_edge_kernel<<<64, 256, 0, stream>>>(edgesA, &ecnt[2], u, sagg);
  topk_kernel<<<1, 1024, 0, stream>>>(sagg, v, br3, score, KP2, KP3, perm, newid, &ecnt[3]);
  gather_kernel<<<KP3, 256, 0, stream>>>(yA, perm, score, yB);
  readout_part<<<32, 256, 0, stream>>>(yB, KP3, pmax, psum);
  readout_fin<<<1, 256, 0, stream>>>(pmax, psum, racc, 1.f / KP3);

  final_kernel<<<2, 256, 0, stream>>>(racc, out);
}

// Round 3
// 415.059 us; speedup vs baseline: 1.4292x; 1.1881x over previous
//
#include <hip/hip_runtime.h>
#include <math.h>

#define N0 4096
#define FDIM 500
#define H 256
#define KP1 3072
#define KP2 2304
#define KP3 1728
#define CAP 131072u
#define KPAD 512

typedef __attribute__((ext_vector_type(8))) short bf16x8;
typedef __attribute__((ext_vector_type(4))) float f32x4;

__device__ inline unsigned short f2bf(float x) {
  unsigned u = __float_as_uint(x);
  unsigned r = (u + 0x7fffu + ((u >> 16) & 1u)) >> 16;
  return (unsigned short)r;
}
__device__ inline float bf2f(unsigned short h) { return __uint_as_float(((unsigned)h) << 16); }

// ---------------- init ----------------
__global__ void init_kernel(float* racc, unsigned* dmax, unsigned* ecnt) {
  int t = threadIdx.x;
  if (t < 512) racc[t] = 0.f;
  if (t == 0) *dmax = 0u;
  if (t < 4) ecnt[t] = 0u;
}

// ---------------- row squared norms ----------------
__global__ void sq_kernel(const float* __restrict__ X, float* __restrict__ sq) {
  int row = blockIdx.x, lane = threadIdx.x;
  float s = 0.f;
  for (int k = lane; k < FDIM; k += 64) { float x = X[(size_t)row * FDIM + k]; s += x * x; }
  for (int off = 32; off; off >>= 1) s += __shfl_down(s, off);
  if (lane == 0) sq[row] = s;
}

// ---------------- split-bf16 conversion: feat -> Xh, Xm [4096][512] ----------------
__global__ void conv_kernel(const float* __restrict__ X, unsigned short* __restrict__ Xh,
                            unsigned short* __restrict__ Xm) {
  int i = blockIdx.x * 256 + threadIdx.x;  // over 4096*512
  int row = i >> 9, k = i & 511;
  float x = (k < FDIM) ? X[(size_t)row * FDIM + k] : 0.f;
  unsigned short h = f2bf(x);
  unsigned short m = f2bf(x - bf2f(h));
  Xh[i] = h;
  Xm[i] = m;
}

// ---------------- W[K x 256] -> Wt split-bf16 [256 x KP] (transposed, zero-padded) ----------------
__global__ void wtconv_kernel(const float* __restrict__ W, int K, int KP,
                              unsigned short* __restrict__ Wth, unsigned short* __restrict__ Wtm) {
  int i = blockIdx.x * 256 + threadIdx.x;  // over 256*KP, c fastest for coalesced W read
  int c = i & 255, k = i >> 8;
  if (k >= KP) return;
  float x = (k < K) ? W[(size_t)k * 256 + c] : 0.f;
  unsigned short h = f2bf(x), m = f2bf(x - bf2f(h));
  Wth[(size_t)c * KP + k] = h;
  Wtm[(size_t)c * KP + k] = m;
}

// ---------------- MFMA distance tiles (split-bf16 Gram), 128x128 tile, lower-tri grid ----------------
template<int PASS>
__global__ __launch_bounds__(256) void distm_kernel(
    const unsigned short* __restrict__ Xh, const unsigned short* __restrict__ Xm,
    const float* __restrict__ sq, float* __restrict__ tmin, unsigned* __restrict__ dmax,
    uint2* __restrict__ edges, unsigned* __restrict__ ecnt) {
  int t = blockIdx.x;
  int bi = (int)((sqrtf(8.f * (float)t + 1.f) - 1.f) * 0.5f);
  while ((bi + 1) * (bi + 2) / 2 <= t) ++bi;
  while (bi * (bi + 1) / 2 > t) --bi;
  int bj = t - bi * (bi + 1) / 2;  // bj <= bi

  float thr = 0.f;
  if (PASS == 1) {
    thr = 0.5f * __uint_as_float(*dmax);
    if (tmin[t] >= thr) return;
  }

  __shared__ unsigned short Lah[128 * 32];
  __shared__ unsigned short Lam[128 * 32];
  __shared__ unsigned short Lbh[128 * 32];
  __shared__ unsigned short Lbm[128 * 32];

  const int tid = threadIdx.x;
  const int lane = tid & 63;
  const int w = tid >> 6;
  const int wr = w >> 1, wc = w & 1;
  const int fr = lane & 15;
  const int kg = lane >> 4;

  const int Ibase = bi * 128, Jbase = bj * 128;

  f32x4 acc[4][4] = {};

  for (int k0 = 0; k0 < KPAD; k0 += 32) {
#pragma unroll
    for (int s = 0; s < 2; ++s) {
      int eo = s * 2048 + tid * 8;
      int row = s * 64 + (tid >> 2);
      int kk = (tid & 3) * 8;
      size_t ga = (size_t)(Ibase + row) * KPAD + k0 + kk;
      size_t gb = (size_t)(Jbase + row) * KPAD + k0 + kk;
      *(bf16x8*)&Lah[eo] = *(const bf16x8*)&Xh[ga];
      *(bf16x8*)&Lam[eo] = *(const bf16x8*)&Xm[ga];
      *(bf16x8*)&Lbh[eo] = *(const bf16x8*)&Xh[gb];
      *(bf16x8*)&Lbm[eo] = *(const bf16x8*)&Xm[gb];
    }
    __syncthreads();
    bf16x8 ah[4], am[4], bh[4], bm[4];
#pragma unroll
    for (int f = 0; f < 4; ++f) {
      int ra = (wr * 64 + f * 16 + fr) * 32 + kg * 8;
      int rb = (wc * 64 + f * 16 + fr) * 32 + kg * 8;
      ah[f] = *(const bf16x8*)&Lah[ra];
      am[f] = *(const bf16x8*)&Lam[ra];
      bh[f] = *(const bf16x8*)&Lbh[rb];
      bm[f] = *(const bf16x8*)&Lbm[rb];
    }
#pragma unroll
    for (int i = 0; i < 4; ++i)
#pragma unroll
      for (int j = 0; j < 4; ++j) {
        acc[i][j] = __builtin_amdgcn_mfma_f32_16x16x32_bf16(ah[i], bh[j], acc[i][j], 0, 0, 0);
        acc[i][j] = __builtin_amdgcn_mfma_f32_16x16x32_bf16(ah[i], bm[j], acc[i][j], 0, 0, 0);
        acc[i][j] = __builtin_amdgcn_mfma_f32_16x16x32_bf16(am[i], bh[j], acc[i][j], 0, 0, 0);
      }
    __syncthreads();
  }

  const int Ib = Ibase + wr * 64, Jb = Jbase + wc * 64;
  const int col = fr, rgrp = kg;  // C/D: col = lane&15, row = (lane>>4)*4 + reg

  float sqj[4];
#pragma unroll
  for (int j = 0; j < 4; ++j) sqj[j] = sq[Jb + j * 16 + col];

  if (PASS == 0) {
    float lmin = INFINITY, lmax = -INFINITY;
#pragma unroll
    for (int i = 0; i < 4; ++i)
#pragma unroll
      for (int r = 0; r < 4; ++r) {
        int gi = Ib + i * 16 + rgrp * 4 + r;
        float sqi = sq[gi];
#pragma unroll
        for (int j = 0; j < 4; ++j) {
          int gj = Jb + j * 16 + col;
          if (gi > gj) {
            float Dv = sqi + sqj[j] - 2.f * acc[i][j][r];
            lmin = fminf(lmin, Dv);
            lmax = fmaxf(lmax, Dv);
          }
        }
      }
    __syncthreads();
    float* red = (float*)Lah;
    red[tid] = lmin;
    red[256 + tid] = lmax;
    __syncthreads();
    for (int s2 = 128; s2 > 0; s2 >>= 1) {
      if (tid < s2) {
        red[tid] = fminf(red[tid], red[tid + s2]);
        red[256 + tid] = fmaxf(red[256 + tid], red[256 + tid + s2]);
      }
      __syncthreads();
    }
    if (tid == 0) {
      tmin[t] = red[0];
      float bmax = red[256];
      if (bmax > 0.f) atomicMax(dmax, __float_as_uint(bmax));
    }
  } else {
#pragma unroll
    for (int i = 0; i < 4; ++i)
#pragma unroll
      for (int r = 0; r < 4; ++r) {
        int gi = Ib + i * 16 + rgrp * 4 + r;
        float sqi = sq[gi];
#pragma unroll
        for (int j = 0; j < 4; ++j) {
          int gj = Jb + j * 16 + col;
          if (gi > gj) {
            float Dv = sqi + sqj[j] - 2.f * acc[i][j][r];
            if (Dv < thr) {
              unsigned p = atomicAdd(ecnt, 1u);
              if (p < CAP) edges[p] = make_uint2((unsigned)gi, (unsigned)gj);
            }
          }
        }
      }
  }
}

// ---------------- MFMA GEMM: C[n x 256] = X @ Wt^T (split-bf16, 128x128 tile) ----------------
__global__ __launch_bounds__(256) void xwm_kernel(
    const unsigned short* __restrict__ Xh, const unsigned short* __restrict__ Xm, int ldx,
    const unsigned short* __restrict__ Wth, const unsigned short* __restrict__ Wtm, int ldw,
    float* __restrict__ C, int ksteps) {
  const int bc = blockIdx.x;   // col block (0..1)
  const int bi = blockIdx.y;   // row block
  __shared__ unsigned short Lah[128 * 32];
  __shared__ unsigned short Lam[128 * 32];
  __shared__ unsigned short Lbh[128 * 32];
  __shared__ unsigned short Lbm[128 * 32];

  const int tid = threadIdx.x;
  const int lane = tid & 63;
  const int w = tid >> 6;
  const int wr = w >> 1, wc = w & 1;
  const int fr = lane & 15;
  const int kg = lane >> 4;

  f32x4 acc[4][4] = {};

  for (int ks = 0; ks < ksteps; ++ks) {
    int k0 = ks * 32;
#pragma unroll
    for (int s = 0; s < 2; ++s) {
      int eo = s * 2048 + tid * 8;
      int row = s * 64 + (tid >> 2);
      int kk = (tid & 3) * 8;
      size_t ga = (size_t)(bi * 128 + row) * ldx + k0 + kk;
      size_t gb = (size_t)(bc * 128 + row) * ldw + k0 + kk;
      *(bf16x8*)&Lah[eo] = *(const bf16x8*)&Xh[ga];
      *(bf16x8*)&Lam[eo] = *(const bf16x8*)&Xm[ga];
      *(bf16x8*)&Lbh[eo] = *(const bf16x8*)&Wth[gb];
      *(bf16x8*)&Lbm[eo] = *(const bf16x8*)&Wtm[gb];
    }
    __syncthreads();
    bf16x8 ah[4], am[4], bh[4], bm[4];
#pragma unroll
    for (int f = 0; f < 4; ++f) {
      int ra = (wr * 64 + f * 16 + fr) * 32 + kg * 8;
      int rb = (wc * 64 + f * 16 + fr) * 32 + kg * 8;
      ah[f] = *(const bf16x8*)&Lah[ra];
      am[f] = *(const bf16x8*)&Lam[ra];
      bh[f] = *(const bf16x8*)&Lbh[rb];
      bm[f] = *(const bf16x8*)&Lbm[rb];
    }
#pragma unroll
    for (int i = 0; i < 4; ++i)
#pragma unroll
      for (int j = 0; j < 4; ++j) {
        acc[i][j] = __builtin_amdgcn_mfma_f32_16x16x32_bf16(ah[i], bh[j], acc[i][j], 0, 0, 0);
        acc[i][j] = __builtin_amdgcn_mfma_f32_16x16x32_bf16(ah[i], bm[j], acc[i][j], 0, 0, 0);
        acc[i][j] = __builtin_amdgcn_mfma_f32_16x16x32_bf16(am[i], bh[j], acc[i][j], 0, 0, 0);
      }
    __syncthreads();
  }

#pragma unroll
  for (int i = 0; i < 4; ++i)
#pragma unroll
    for (int r = 0; r < 4; ++r) {
      int gr = bi * 128 + wr * 64 + i * 16 + kg * 4 + r;
#pragma unroll
      for (int j = 0; j < 4; ++j) {
        int gc = bc * 128 + wc * 64 + j * 16 + fr;
        C[(size_t)gr * H + gc] = acc[i][j][r];
      }
    }
}

// ---------------- small helpers ----------------
__global__ void fill_kernel(float* p, float val, int n) {
  int i = blockIdx.x * 256 + threadIdx.x;
  if (i < n) p[i] = val;
}
__global__ void deg_edge_kernel(const uint2* edges, const unsigned* ecnt, float* deg) {
  unsigned c = *ecnt; if (c > CAP) c = CAP;
  for (unsigned e = blockIdx.x * 256 + threadIdx.x; e < c; e += gridDim.x * 256)
    atomicAdd(&deg[edges[e].x], 1.f);
}
__global__ void rsqrt_kernel(float* d, const float* deg, int n) {
  int i = blockIdx.x * 256 + threadIdx.x;
  if (i < n) d[i] = rsqrtf(deg[i]);
}
__global__ void gcn_base_kernel(const float* __restrict__ xW, const float* __restrict__ dinv, float* __restrict__ tmp) {
  int i = blockIdx.x, h = threadIdx.x;
  float di = dinv[i];
  tmp[(size_t)i * H + h] = di * di * xW[(size_t)i * H + h];
}
__global__ void gcn_edge_kernel(const uint2* edges, const unsigned* ecnt,
                                const float* __restrict__ xW, const float* __restrict__ dinv, float* tmp) {
  unsigned c = *ecnt; if (c > CAP) c = CAP;
  int h = threadIdx.x;
  for (unsigned e = blockIdx.x; e < c; e += gridDim.x) {
    uint2 ed = edges[e];
    float wgt = dinv[ed.x] * dinv[ed.y];
    atomicAdd(&tmp[(size_t)ed.x * H + h], wgt * xW[(size_t)ed.y * H + h]);
  }
}
__global__ void relu_bias_kernel(const float* __restrict__ tmp, const float* __restrict__ b, float* __restrict__ y) {
  int i = blockIdx.x, h = threadIdx.x;
  y[(size_t)i * H + h] = fmaxf(tmp[(size_t)i * H + h] + b[h], 0.f);
}
__global__ void uv_kernel(const float* __restrict__ y, const float* __restrict__ Wr,
                          const float* __restrict__ Ws, float* u, float* v, float* sagg) {
  int node = blockIdx.x, lane = threadIdx.x;  // 64 lanes
  float4 a = ((const float4*)(y + (size_t)node * H))[lane];
  float4 wr = ((const float4*)Wr)[lane];
  float4 ws = ((const float4*)Ws)[lane];
  float du = a.x * wr.x + a.y * wr.y + a.z * wr.z + a.w * wr.w;
  float dv = a.x * ws.x + a.y * ws.y + a.z * ws.z + a.w * ws.w;
  for (int off = 32; off; off >>= 1) { du += __shfl_down(du, off); dv += __shfl_down(dv, off); }
  if (lane == 0) { u[node] = du; v[node] = dv; sagg[node] = 0.f; }
}
__global__ void score_edge_kernel(const uint2* edges, const unsigned* ecnt, const float* u, float* sagg) {
  unsigned c = *ecnt; if (c > CAP) c = CAP;
  for (unsigned e = blockIdx.x * 256 + threadIdx.x; e < c; e += gridDim.x * 256) {
    uint2 ed = edges[e];
    atomicAdd(&sagg[ed.x], u[ed.y]);
  }
}

// ---------------- top-k (score fused): single-block bitonic sort of 4096 packed keys ----------------
__global__ __launch_bounds__(1024) void topk_kernel(const float* __restrict__ sagg, const float* __restrict__ v,
                                                    const float* __restrict__ br, float* __restrict__ score,
                                                    int n, int k, int* perm, int* newid, unsigned* nextcnt) {
  __shared__ unsigned long long keys[4096];
  int tid = threadIdx.x;
  float brv = br[0];
  for (int i = tid; i < 4096; i += 1024) {
    float s = -INFINITY;
    if (i < n) { s = tanhf(sagg[i] + brv + v[i]); score[i] = s; }
    unsigned b = __float_as_uint(s);
    unsigned sortable = b ^ ((b & 0x80000000u) ? 0xFFFFFFFFu : 0x80000000u);
    keys[i] = ((unsigned long long)(~sortable) << 32) | (unsigned)i;
  }
  __syncthreads();
  for (int kk = 2; kk <= 4096; kk <<= 1) {
    for (int j = kk >> 1; j > 0; j >>= 1) {
      for (int i = tid; i < 4096; i += 1024) {
        int l = i ^ j;
        if (l > i) {
          unsigned long long a = keys[i], c = keys[l];
          bool up = ((i & kk) == 0);
          if ((a > c) == up) { keys[i] = c; keys[l] = a; }
        }
      }
      __syncthreads();
    }
  }
  for (int r = tid; r < 4096; r += 1024) {
    if (r < n) {
      int old = (int)(keys[r] & 0xFFFFFFFFu);
      newid[old] = (r < k) ? r : -1;
      if (r < k) perm[r] = old;
    }
  }
  if (tid == 0 && nextcnt) *nextcnt = 0u;
}

// gather pooled rows; also emit split-bf16 copy for next layer's MFMA GEMM
__global__ void gather_kernel(const float* __restrict__ y, const int* __restrict__ perm,
                              const float* __restrict__ score, float* __restrict__ xs,
                              unsigned short* __restrict__ Yh, unsigned short* __restrict__ Ym) {
  int r = blockIdx.x, h = threadIdx.x;
  int old = perm[r];
  float vv = y[(size_t)old * H + h] * score[old];
  xs[(size_t)r * H + h] = vv;
  unsigned short hh = f2bf(vv);
  Yh[(size_t)r * H + h] = hh;
  Ym[(size_t)r * H + h] = f2bf(vv - bf2f(hh));
}
__global__ void filter_kernel(const uint2* in, const unsigned* incnt, const int* __restrict__ newid,
                              uint2* out, unsigned* outcnt) {
  unsigned c = *incnt; if (c > CAP) c = CAP;
  unsigned e = blockIdx.x * 256 + threadIdx.x;
  if (e < c) {
    uint2 ed = in[e];
    int nt = newid[ed.x], ns = newid[ed.y];
    if (nt >= 0 && ns >= 0) {
      unsigned p = atomicAdd(outcnt, 1u);
      if (p < CAP) out[p] = make_uint2((unsigned)nt, (unsigned)ns);
    }
  }
}

// ---------------- readout (col max + mean), 2-stage ----------------
__global__ void readout_part(const float* __restrict__ xs, int k, float* pmax, float* psum) {
  int h = threadIdx.x, b = blockIdx.x;  // 32 blocks x 256 threads
  float m = -INFINITY, s = 0.f;
  for (int r = b; r < k; r += 32) {
    float vv = xs[(size_t)r * H + h];
    m = fmaxf(m, vv);
    s += vv;
  }
  pmax[b * H + h] = m;
  psum[b * H + h] = s;
}
__global__ void readout_fin(const float* pmax, const float* psum, float* racc, float invk) {
  int h = threadIdx.x;
  float m = -INFINITY, s = 0.f;
  for (int b = 0; b < 32; ++b) { m = fmaxf(m, pmax[b * H + h]); s += psum[b * H + h]; }
  racc[h] += m;
  racc[H + h] += s * invk;
}
__global__ void final_kernel(const float* racc, float* out) {
  int t = blockIdx.x * 256 + threadIdx.x;
  if (t < 512) out[t] = racc[t];
}

extern "C" void kernel_launch(void* const* d_in, const int* in_sizes, int n_in,
                              void* d_out, int out_size, void* d_ws, size_t ws_size,
                              hipStream_t stream) {
  const float* feat = (const float*)d_in[0];
  const float* W1 = (const float*)d_in[1];  const float* b1 = (const float*)d_in[2];
  const float* W2 = (const float*)d_in[3];  const float* b2 = (const float*)d_in[4];
  const float* W3 = (const float*)d_in[5];  const float* b3 = (const float*)d_in[6];
  const float* Wr1 = (const float*)d_in[7]; const float* br1 = (const float*)d_in[8]; const float* Ws1 = (const float*)d_in[9];
  const float* Wr2 = (const float*)d_in[10]; const float* br2 = (const float*)d_in[11]; const float* Ws2 = (const float*)d_in[12];
  const float* Wr3 = (const float*)d_in[13]; const float* br3 = (const float*)d_in[14]; const float* Ws3 = (const float*)d_in[15];
  float* out = (float*)d_out;

  char* w = (char*)d_ws;
  size_t o = 0;
  auto alloc = [&](size_t bytes) { size_t cur = o; o += (bytes + 255) & ~(size_t)255; return cur; };
  float* racc  = (float*)(w + alloc(512 * 4));
  unsigned* dmax = (unsigned*)(w + alloc(4));
  unsigned* ecnt = (unsigned*)(w + alloc(4 * 4));
  float* sq    = (float*)(w + alloc(N0 * 4));
  float* tmin  = (float*)(w + alloc(4096 * 4));
  float* deg   = (float*)(w + alloc(N0 * 4));
  float* dinv  = (float*)(w + alloc(N0 * 4));
  float* u     = (float*)(w + alloc(N0 * 4));
  float* v     = (float*)(w + alloc(N0 * 4));
  float* sagg  = (float*)(w + alloc(N0 * 4));
  float* score = (float*)(w + alloc(N0 * 4));
  int* perm    = (int*)(w + alloc(N0 * 4));
  int* newid   = (int*)(w + alloc(N0 * 4));
  float* pmax  = (float*)(w + alloc(32 * H * 4));
  float* psum  = (float*)(w + alloc(32 * H * 4));
  uint2* edgesA = (uint2*)(w + alloc(CAP * 8));
  uint2* edgesB = (uint2*)(w + alloc(CAP * 8));
  unsigned short* Wth = (unsigned short*)(w + alloc(256 * KPAD * 2));
  unsigned short* Wtm = (unsigned short*)(w + alloc(256 * KPAD * 2));
  float* xW = (float*)(w + alloc((size_t)N0 * H * 4));
  float* tmp = (float*)(w + alloc((size_t)N0 * H * 4));
  float* yA = (float*)(w + alloc((size_t)N0 * H * 4));   // overlay: Xh (dist/layer1 GEMM lifetime)
  float* yB = (float*)(w + alloc((size_t)N0 * H * 4));   // overlay: Xm

  unsigned short* Xh = (unsigned short*)yA;   // [4096][512] bf16
  unsigned short* Xm = (unsigned short*)yB;
  // pooled split-bf16 overlays tmp's dead window [after relu_L .. before gcn_base_{L+1}]
  unsigned short* Yh = (unsigned short*)tmp;                       // [<=4096][256] bf16 (2MB)
  unsigned short* Ym = (unsigned short*)((char*)tmp + 2097152);

  init_kernel<<<1, 512, 0, stream>>>(racc, dmax, ecnt);
  sq_kernel<<<N0, 64, 0, stream>>>(feat, sq);
  conv_kernel<<<(N0 * KPAD) / 256, 256, 0, stream>>>(feat, Xh, Xm);
  distm_kernel<0><<<528, 256, 0, stream>>>(Xh, Xm, sq, tmin, dmax, edgesA, ecnt);
  distm_kernel<1><<<528, 256, 0, stream>>>(Xh, Xm, sq, tmin, dmax, edgesA, ecnt);

  // ---- layer 1: n=N0, edges=edgesA(ecnt0) -> pooled k=KP1, edgesB(ecnt1)
  wtconv_kernel<<<KPAD, 256, 0, stream>>>(W1, FDIM, KPAD, Wth, Wtm);
  xwm_kernel<<<dim3(2, N0 / 128), 256, 0, stream>>>(Xh, Xm, KPAD, Wth, Wtm, KPAD, xW, KPAD / 32);
  fill_kernel<<<(N0 + 255) / 256, 256, 0, stream>>>(deg, 1.f, N0);
  deg_edge_kernel<<<64, 256, 0, stream>>>(edgesA, &ecnt[0], deg);
  rsqrt_kernel<<<(N0 + 255) / 256, 256, 0, stream>>>(dinv, deg, N0);
  gcn_base_kernel<<<N0, 256, 0, stream>>>(xW, dinv, tmp);
  gcn_edge_kernel<<<256, 256, 0, stream>>>(edgesA, &ecnt[0], xW, dinv, tmp);
  relu_bias_kernel<<<N0, 256, 0, stream>>>(tmp, b1, yA);
  uv_kernel<<<N0, 64, 0, stream>>>(yA, Wr1, Ws1, u, v, sagg);
  score_edge_kernel<<<64, 256, 0, stream>>>(edgesA, &ecnt[0], u, sagg);
  topk_kernel<<<1, 1024, 0, stream>>>(sagg, v, br1, score, N0, KP1, perm, newid, &ecnt[1]);
  gather_kernel<<<KP1, 256, 0, stream>>>(yA, perm, score, yB, Yh, Ym);
  filter_kernel<<<CAP / 256, 256, 0, stream>>>(edgesA, &ecnt[0], newid, edgesB, &ecnt[1]);
  readout_part<<<32, 256, 0, stream>>>(yB, KP1, pmax, psum);
  readout_fin<<<1, 256, 0, stream>>>(pmax, psum, racc, 1.f / KP1);

  // ---- layer 2: n=KP1, edges=edgesB(ecnt1) -> pooled k=KP2, edgesA(ecnt2)
  wtconv_kernel<<<H, 256, 0, stream>>>(W2, H, H, Wth, Wtm);
  xwm_kernel<<<dim3(2, KP1 / 128), 256, 0, stream>>>(Yh, Ym, H, Wth, Wtm, H, xW, H / 32);
  fill_kernel<<<(KP1 + 255) / 256, 256, 0, stream>>>(deg, 1.f, KP1);
  deg_edge_kernel<<<64, 256, 0, stream>>>(edgesB, &ecnt[1], deg);
  rsqrt_kernel<<<(KP1 + 255) / 256, 256, 0, stream>>>(dinv, deg, KP1);
  gcn_base_kernel<<<KP1, 256, 0, stream>>>(xW, dinv, tmp);
  gcn_edge_kernel<<<256, 256, 0, stream>>>(edgesB, &ecnt[1], xW, dinv, tmp);
  relu_bias_kernel<<<KP1, 256, 0, stream>>>(tmp, b2, yA);
  uv_kernel<<<KP1, 64, 0, stream>>>(yA, Wr2, Ws2, u, v, sagg);
  score_edge_kernel<<<64, 256, 0, stream>>>(edgesB, &ecnt[1], u, sagg);
  topk_kernel<<<1, 1024, 0, stream>>>(sagg, v, br2, score, KP1, KP2, perm, newid, &ecnt[2]);
  gather_kernel<<<KP2, 256, 0, stream>>>(yA, perm, score, yB, Yh, Ym);
  filter_kernel<<<CAP / 256, 256, 0, stream>>>(edgesB, &ecnt[1], newid, edgesA, &ecnt[2]);
  readout_part<<<32, 256, 0, stream>>>(yB, KP2, pmax, psum);
  readout_fin<<<1, 256, 0, stream>>>(pmax, psum, racc, 1.f / KP2);

  // ---- layer 3: n=KP2, edges=edgesA(ecnt2) -> pooled k=KP3
  wtconv_kernel<<<H, 256, 0, stream>>>(W3, H, H, Wth, Wtm);
  xwm_kernel<<<dim3(2, KP2 / 128), 256, 0, stream>>>(Yh, Ym, H, Wth, Wtm, H, xW, H / 32);
  fill_kernel<<<(KP2 + 255) / 256, 256, 0, stream>>>(deg, 1.f, KP2);
  deg_edge_kernel<<<64, 256, 0, stream>>>(edgesA, &ecnt[2], deg);
  rsqrt_kernel<<<(KP2 + 255) / 256, 256, 0, stream>>>(dinv, deg, KP2);
  gcn_base_kernel<<<KP2, 256, 0, stream>>>(xW, dinv, tmp);
  gcn_edge_kernel<<<256, 256, 0, stream>>>(edgesA, &ecnt[2], xW, dinv, tmp);
  relu_bias_kernel<<<KP2, 256, 0, stream>>>(tmp, b3, yA);
  uv_kernel<<<KP2, 64, 0, stream>>>(yA, Wr3, Ws3, u, v, sagg);
  score_edge_kernel<<<64, 256, 0, stream>>>(edgesA, &ecnt[2], u, sagg);
  topk_kernel<<<1, 1024, 0, stream>>>(sagg, v, br3, score, KP2, KP3, perm, newid, &ecnt[3]);
  gather_kernel<<<KP3, 256, 0, stream>>>(yA, perm, score, yB, Yh, Ym);
  readout_part<<<32, 256, 0, stream>>>(yB, KP3, pmax, psum);
  readout_fin<<<1, 256, 0, stream>>>(pmax, psum, racc, 1.f / KP3);

  final_kernel<<<2, 256, 0, stream>>>(racc, out);
}

// Round 4
// 292.127 us; speedup vs baseline: 2.0306x; 1.4208x over previous
//
#include <hip/hip_runtime.h>
#include <math.h>

#define N0 4096
#define FDIM 500
#define H 256
#define KP1 3072
#define KP2 2304
#define KP3 1728
#define CAP 131072u
#define KPAD 512

typedef __attribute__((ext_vector_type(8))) short bf16x8;
typedef __attribute__((ext_vector_type(4))) float f32x4;
typedef unsigned short ush;
typedef unsigned long long u64;

__device__ inline ush f2bf(float x) {
  unsigned u = __float_as_uint(x);
  unsigned r = (u + 0x7fffu + ((u >> 16) & 1u)) >> 16;
  return (ush)r;
}
__device__ inline float bf2f(ush h) { return __uint_as_float(((unsigned)h) << 16); }

// ---------------- init ----------------
__global__ void init_kernel(float* racc, unsigned* dmax, unsigned* ecnt) {
  int t = threadIdx.x;
  if (t < 512) racc[t] = 0.f;
  if (t == 0) *dmax = 0u;
  if (t < 4) ecnt[t] = 0u;
}

// ---------------- fused split-bf16 conversion + row sq-norm: one block per row ----------------
__global__ void convsq_kernel(const float* __restrict__ X, ush* __restrict__ Xh,
                              ush* __restrict__ Xm, float* __restrict__ sq) {
  int row = blockIdx.x, t = threadIdx.x;  // 256 threads, 2 elems each
  float s = 0.f;
#pragma unroll
  for (int e = 0; e < 2; ++e) {
    int kx = t + e * 256;
    float x = (kx < FDIM) ? X[(size_t)row * FDIM + kx] : 0.f;
    ush h = f2bf(x);
    Xh[(size_t)row * KPAD + kx] = h;
    Xm[(size_t)row * KPAD + kx] = f2bf(x - bf2f(h));
    s += x * x;
  }
  for (int off = 32; off; off >>= 1) s += __shfl_down(s, off);
  __shared__ float sw[4];
  if ((t & 63) == 0) sw[t >> 6] = s;
  __syncthreads();
  if (t == 0) sq[row] = sw[0] + sw[1] + sw[2] + sw[3];
}

// ---------------- all three W -> Wt split-bf16 (transposed, padded) in one launch ----------------
__global__ void wtconv_all_kernel(const float* __restrict__ W1, const float* __restrict__ W2,
                                  const float* __restrict__ W3,
                                  ush* Wth1, ush* Wtm1, ush* Wth2, ush* Wtm2, ush* Wth3, ush* Wtm3) {
  int blk = blockIdx.x, c = threadIdx.x;
  const float* W; ush *Ph, *Pm; int K, KP, k;
  if (blk < 512)      { W = W1; Ph = Wth1; Pm = Wtm1; K = FDIM; KP = 512; k = blk; }
  else if (blk < 768) { W = W2; Ph = Wth2; Pm = Wtm2; K = 256;  KP = 256; k = blk - 512; }
  else                { W = W3; Ph = Wth3; Pm = Wtm3; K = 256;  KP = 256; k = blk - 768; }
  float x = (k < K) ? W[(size_t)k * 256 + c] : 0.f;
  ush h = f2bf(x);
  Ph[(size_t)c * KP + k] = h;
  Pm[(size_t)c * KP + k] = f2bf(x - bf2f(h));
}

// ---------------- MFMA distance tiles, 128x128 tile, 512 threads (8 waves) ----------------
template<int PASS>
__global__ __launch_bounds__(512) void distm_kernel(
    const ush* __restrict__ Xh, const ush* __restrict__ Xm,
    const float* __restrict__ sq, float* __restrict__ tmin, unsigned* __restrict__ dmax,
    uint2* __restrict__ edges, unsigned* __restrict__ ecnt) {
  int t = blockIdx.x;
  int bi = (int)((sqrtf(8.f * (float)t + 1.f) - 1.f) * 0.5f);
  while ((bi + 1) * (bi + 2) / 2 <= t) ++bi;
  while (bi * (bi + 1) / 2 > t) --bi;
  int bj = t - bi * (bi + 1) / 2;  // bj <= bi

  float thr = 0.f;
  if (PASS == 1) {
    thr = 0.5f * __uint_as_float(*dmax);
    if (tmin[t] >= thr) return;
  }

  __shared__ ush Lah[128 * 32];
  __shared__ ush Lam[128 * 32];
  __shared__ ush Lbh[128 * 32];
  __shared__ ush Lbm[128 * 32];

  const int tid = threadIdx.x;
  const int lane = tid & 63;
  const int w = tid >> 6;          // 0..7
  const int wr = w >> 1;           // 0..3 (32-row strip)
  const int wc = w & 1;            // 0..1 (64-col strip)
  const int fr = lane & 15;
  const int kg = lane >> 4;

  const int Ibase = bi * 128, Jbase = bj * 128;

  f32x4 acc[2][4] = {};

  for (int k0 = 0; k0 < KPAD; k0 += 32) {
    {
      int eo = tid * 8;
      int row = tid >> 2;
      int kk = (tid & 3) * 8;
      size_t ga = (size_t)(Ibase + row) * KPAD + k0 + kk;
      size_t gb = (size_t)(Jbase + row) * KPAD + k0 + kk;
      *(bf16x8*)&Lah[eo] = *(const bf16x8*)&Xh[ga];
      *(bf16x8*)&Lam[eo] = *(const bf16x8*)&Xm[ga];
      *(bf16x8*)&Lbh[eo] = *(const bf16x8*)&Xh[gb];
      *(bf16x8*)&Lbm[eo] = *(const bf16x8*)&Xm[gb];
    }
    __syncthreads();
    bf16x8 ah[2], am[2], bh[4], bm[4];
#pragma unroll
    for (int f = 0; f < 2; ++f) {
      int ra = (wr * 32 + f * 16 + fr) * 32 + kg * 8;
      ah[f] = *(const bf16x8*)&Lah[ra];
      am[f] = *(const bf16x8*)&Lam[ra];
    }
#pragma unroll
    for (int f = 0; f < 4; ++f) {
      int rb = (wc * 64 + f * 16 + fr) * 32 + kg * 8;
      bh[f] = *(const bf16x8*)&Lbh[rb];
      bm[f] = *(const bf16x8*)&Lbm[rb];
    }
#pragma unroll
    for (int i = 0; i < 2; ++i)
#pragma unroll
      for (int j = 0; j < 4; ++j) {
        acc[i][j] = __builtin_amdgcn_mfma_f32_16x16x32_bf16(ah[i], bh[j], acc[i][j], 0, 0, 0);
        acc[i][j] = __builtin_amdgcn_mfma_f32_16x16x32_bf16(ah[i], bm[j], acc[i][j], 0, 0, 0);
        acc[i][j] = __builtin_amdgcn_mfma_f32_16x16x32_bf16(am[i], bh[j], acc[i][j], 0, 0, 0);
      }
    __syncthreads();
  }

  const int Ib = Ibase + wr * 32, Jb = Jbase + wc * 64;
  const int col = fr, rgrp = kg;  // C/D: col = lane&15, row = (lane>>4)*4 + reg

  float sqj[4];
#pragma unroll
  for (int j = 0; j < 4; ++j) sqj[j] = sq[Jb + j * 16 + col];

  if (PASS == 0) {
    float lmin = INFINITY, lmax = -INFINITY;
#pragma unroll
    for (int i = 0; i < 2; ++i)
#pragma unroll
      for (int r = 0; r < 4; ++r) {
        int gi = Ib + i * 16 + rgrp * 4 + r;
        float sqi = sq[gi];
#pragma unroll
        for (int j = 0; j < 4; ++j) {
          int gj = Jb + j * 16 + col;
          if (gi > gj) {
            float Dv = sqi + sqj[j] - 2.f * acc[i][j][r];
            lmin = fminf(lmin, Dv);
            lmax = fmaxf(lmax, Dv);
          }
        }
      }
    __syncthreads();
    float* red = (float*)Lah;
    red[tid] = lmin;
    red[512 + tid] = lmax;
    __syncthreads();
    for (int s2 = 256; s2 > 0; s2 >>= 1) {
      if (tid < s2) {
        red[tid] = fminf(red[tid], red[tid + s2]);
        red[512 + tid] = fmaxf(red[512 + tid], red[512 + tid + s2]);
      }
      __syncthreads();
    }
    if (tid == 0) {
      tmin[t] = red[0];
      float bmax = red[512];
      if (bmax > 0.f) atomicMax(dmax, __float_as_uint(bmax));  // positive: uint order == float order
    }
  } else {
#pragma unroll
    for (int i = 0; i < 2; ++i)
#pragma unroll
      for (int r = 0; r < 4; ++r) {
        int gi = Ib + i * 16 + rgrp * 4 + r;
        float sqi = sq[gi];
#pragma unroll
        for (int j = 0; j < 4; ++j) {
          int gj = Jb + j * 16 + col;
          if (gi > gj) {
            float Dv = sqi + sqj[j] - 2.f * acc[i][j][r];
            if (Dv < thr) {
              unsigned p = atomicAdd(ecnt, 1u);
              if (p < CAP) edges[p] = make_uint2((unsigned)gi, (unsigned)gj);
            }
          }
        }
      }
  }
}

// ---------------- MFMA GEMM: C[n x 256] = X @ Wt^T (split-bf16, 128x128 tile) ----------------
__global__ __launch_bounds__(256) void xwm_kernel(
    const ush* __restrict__ Xh, const ush* __restrict__ Xm, int ldx,
    const ush* __restrict__ Wth, const ush* __restrict__ Wtm, int ldw,
    float* __restrict__ C, int ksteps) {
  const int bc = blockIdx.x;
  const int bi = blockIdx.y;
  __shared__ ush Lah[128 * 32];
  __shared__ ush Lam[128 * 32];
  __shared__ ush Lbh[128 * 32];
  __shared__ ush Lbm[128 * 32];

  const int tid = threadIdx.x;
  const int lane = tid & 63;
  const int w = tid >> 6;
  const int wr = w >> 1, wc = w & 1;
  const int fr = lane & 15;
  const int kg = lane >> 4;

  f32x4 acc[4][4] = {};

  for (int ks = 0; ks < ksteps; ++ks) {
    int k0 = ks * 32;
#pragma unroll
    for (int s = 0; s < 2; ++s) {
      int eo = s * 2048 + tid * 8;
      int row = s * 64 + (tid >> 2);
      int kk = (tid & 3) * 8;
      size_t ga = (size_t)(bi * 128 + row) * ldx + k0 + kk;
      size_t gb = (size_t)(bc * 128 + row) * ldw + k0 + kk;
      *(bf16x8*)&Lah[eo] = *(const bf16x8*)&Xh[ga];
      *(bf16x8*)&Lam[eo] = *(const bf16x8*)&Xm[ga];
      *(bf16x8*)&Lbh[eo] = *(const bf16x8*)&Wth[gb];
      *(bf16x8*)&Lbm[eo] = *(const bf16x8*)&Wtm[gb];
    }
    __syncthreads();
    bf16x8 ah[4], am[4], bh[4], bm[4];
#pragma unroll
    for (int f = 0; f < 4; ++f) {
      int ra = (wr * 64 + f * 16 + fr) * 32 + kg * 8;
      int rb = (wc * 64 + f * 16 + fr) * 32 + kg * 8;
      ah[f] = *(const bf16x8*)&Lah[ra];
      am[f] = *(const bf16x8*)&Lam[ra];
      bh[f] = *(const bf16x8*)&Lbh[rb];
      bm[f] = *(const bf16x8*)&Lbm[rb];
    }
#pragma unroll
    for (int i = 0; i < 4; ++i)
#pragma unroll
      for (int j = 0; j < 4; ++j) {
        acc[i][j] = __builtin_amdgcn_mfma_f32_16x16x32_bf16(ah[i], bh[j], acc[i][j], 0, 0, 0);
        acc[i][j] = __builtin_amdgcn_mfma_f32_16x16x32_bf16(ah[i], bm[j], acc[i][j], 0, 0, 0);
        acc[i][j] = __builtin_amdgcn_mfma_f32_16x16x32_bf16(am[i], bh[j], acc[i][j], 0, 0, 0);
      }
    __syncthreads();
  }

#pragma unroll
  for (int i = 0; i < 4; ++i)
#pragma unroll
    for (int r = 0; r < 4; ++r) {
      int gr = bi * 128 + wr * 64 + i * 16 + kg * 4 + r;
#pragma unroll
      for (int j = 0; j < 4; ++j) {
        int gc = bc * 128 + wc * 64 + j * 16 + fr;
        C[(size_t)gr * H + gc] = acc[i][j][r];
      }
    }
}

// ---------------- fused deg+rsqrt: single block, LDS degrees ----------------
__global__ __launch_bounds__(1024) void degdinv_kernel(const uint2* __restrict__ edges,
                                                       const unsigned* __restrict__ ecnt,
                                                       float* __restrict__ dinv, int n) {
  __shared__ float degL[4096];
  int tid = threadIdx.x;
  for (int i = tid; i < n; i += 1024) degL[i] = 1.f;
  __syncthreads();
  unsigned c = *ecnt; if (c > CAP) c = CAP;
  for (unsigned e = tid; e < c; e += 1024) atomicAdd(&degL[edges[e].x], 1.f);
  __syncthreads();
  for (int i = tid; i < n; i += 1024) dinv[i] = rsqrtf(degL[i]);
}

__global__ void gcn_base_kernel(const float* __restrict__ xW, const float* __restrict__ dinv,
                                float* __restrict__ tmp) {
  int i = blockIdx.x, h = threadIdx.x;
  float di = dinv[i];
  tmp[(size_t)i * H + h] = di * di * xW[(size_t)i * H + h];
}
__global__ void gcn_edge_kernel(const uint2* edges, const unsigned* ecnt,
                                const float* __restrict__ xW, const float* __restrict__ dinv, float* tmp) {
  unsigned c = *ecnt; if (c > CAP) c = CAP;
  int h = threadIdx.x;
  for (unsigned e = blockIdx.x; e < c; e += gridDim.x) {
    uint2 ed = edges[e];
    float wgt = dinv[ed.x] * dinv[ed.y];
    atomicAdd(&tmp[(size_t)ed.x * H + h], wgt * xW[(size_t)ed.y * H + h]);
  }
}

// ---------------- fused relu+bias + u,v projections ----------------
__global__ void relu_uv_kernel(const float* __restrict__ tmp, const float* __restrict__ b,
                               const float* __restrict__ Wr, const float* __restrict__ Ws,
                               float* __restrict__ y, float* __restrict__ u, float* __restrict__ v) {
  int i = blockIdx.x, t = threadIdx.x;
  float val = fmaxf(tmp[(size_t)i * H + t] + b[t], 0.f);
  y[(size_t)i * H + t] = val;
  float uu = val * Wr[t], vv = val * Ws[t];
  for (int off = 32; off; off >>= 1) { uu += __shfl_down(uu, off); vv += __shfl_down(vv, off); }
  __shared__ float su[4], sv[4];
  if ((t & 63) == 0) { su[t >> 6] = uu; sv[t >> 6] = vv; }
  __syncthreads();
  if (t == 0) {
    u[i] = su[0] + su[1] + su[2] + su[3];
    v[i] = sv[0] + sv[1] + sv[2] + sv[3];
  }
}

// ---------------- fused score + exact top-k (radix select) + deterministic compaction ----------------
// key = (sortable(score) << 32) | (~idx)  -> unique; top-k SET identical to (score desc, idx asc).
__global__ __launch_bounds__(1024) void select_kernel(
    const uint2* __restrict__ edges, const unsigned* __restrict__ ecnt_cur,
    const float* __restrict__ u, const float* __restrict__ v, const float* __restrict__ br,
    float* __restrict__ score, int n, int k, int* __restrict__ newid, unsigned* __restrict__ nextcnt) {
  __shared__ u64 keys[4096];
  __shared__ float saggL[4096];
  __shared__ unsigned hist[256];
  __shared__ unsigned ss[256];
  __shared__ unsigned bsel, brem;
  __shared__ int wredI[16];

  int tid = threadIdx.x;
  for (int i = tid; i < 4096; i += 1024) saggL[i] = 0.f;
  __syncthreads();
  unsigned c = *ecnt_cur; if (c > CAP) c = CAP;
  for (unsigned e = tid; e < c; e += 1024) {
    uint2 ed = edges[e];
    atomicAdd(&saggL[ed.x], u[ed.y]);
  }
  if (tid == 0 && nextcnt) *nextcnt = 0u;
  __syncthreads();

  float brv = br[0];
#pragma unroll
  for (int e = 0; e < 4; ++e) {
    int i = tid * 4 + e;
    float s = -INFINITY;
    if (i < n) { s = tanhf(saggL[i] + brv + v[i]); score[i] = s; }
    unsigned ub = __float_as_uint(s);
    unsigned so = (ub & 0x80000000u) ? ~ub : (ub | 0x80000000u);
    keys[i] = ((u64)so << 32) | (unsigned)(0xFFFFFFFFu - (unsigned)i);
  }
  __syncthreads();

  // 8-level radix select for k-th largest key
  u64 prefix = 0ull;
  unsigned remaining = (unsigned)k;
  for (int b = 7; b >= 0; --b) {
    if (tid < 256) hist[tid] = 0u;
    __syncthreads();
    int sh = (b + 1) * 8;
#pragma unroll
    for (int e = 0; e < 4; ++e) {
      u64 kk = keys[tid * 4 + e];
      bool match = (b == 7) || ((kk >> sh) == (prefix >> sh));
      if (match) atomicAdd(&hist[(unsigned)((kk >> (b * 8)) & 0xFFull)], 1u);
    }
    __syncthreads();
    if (tid < 256) ss[tid] = hist[tid];
    __syncthreads();
    for (int off = 1; off < 256; off <<= 1) {
      unsigned add = 0;
      if (tid < 256 && tid + off < 256) add = ss[tid + off];
      __syncthreads();
      if (tid < 256) ss[tid] += add;
      __syncthreads();
    }
    if (tid < 256) {
      unsigned above = (tid == 255) ? 0u : ss[tid + 1];
      if (ss[tid] >= remaining && above < remaining) { bsel = (unsigned)tid; brem = remaining - above; }
    }
    __syncthreads();
    prefix |= ((u64)bsel) << (b * 8);
    remaining = brem;
    __syncthreads();
  }
  u64 kth = prefix;

  // deterministic compaction: slot = rank among selected by ascending node index
  int flag[4]; int ct = 0;
#pragma unroll
  for (int e = 0; e < 4; ++e) {
    int i = tid * 4 + e;
    int f = (i < n && keys[i] >= kth) ? 1 : 0;
    flag[e] = f; ct += f;
  }
  int lane = tid & 63, wv = tid >> 6;
  int x = ct;
  for (int off = 1; off < 64; off <<= 1) {
    int yv = __shfl_up(x, off, 64);
    if (lane >= off) x += yv;
  }
  if (lane == 63) wredI[wv] = x;
  __syncthreads();
  if (tid == 0) {
    int s = 0;
    for (int q = 0; q < 16; ++q) { int t2 = wredI[q]; wredI[q] = s; s += t2; }
  }
  __syncthreads();
  int base = wredI[wv] + (x - ct);
#pragma unroll
  for (int e = 0; e < 4; ++e) {
    int i = tid * 4 + e;
    if (i < n) {
      if (flag[e]) { newid[i] = base; ++base; }
      else newid[i] = -1;
    }
  }
}

// gather selected rows into compacted slots; emit split-bf16 for next GEMM
__global__ void gather_kernel(const float* __restrict__ y, const int* __restrict__ newid,
                              const float* __restrict__ score, float* __restrict__ xs,
                              ush* __restrict__ Yh, ush* __restrict__ Ym) {
  int i = blockIdx.x;
  int slot = newid[i];
  if (slot < 0) return;
  int h = threadIdx.x;
  float vv = y[(size_t)i * H + h] * score[i];
  xs[(size_t)slot * H + h] = vv;
  ush hh = f2bf(vv);
  Yh[(size_t)slot * H + h] = hh;
  Ym[(size_t)slot * H + h] = f2bf(vv - bf2f(hh));
}
__global__ void filter_kernel(const uint2* in, const unsigned* incnt, const int* __restrict__ newid,
                              uint2* out, unsigned* outcnt) {
  unsigned c = *incnt; if (c > CAP) c = CAP;
  unsigned e = blockIdx.x * 256 + threadIdx.x;
  if (e < c) {
    uint2 ed = in[e];
    int nt = newid[ed.x], ns = newid[ed.y];
    if (nt >= 0 && ns >= 0) {
      unsigned p = atomicAdd(outcnt, 1u);
      if (p < CAP) out[p] = make_uint2((unsigned)nt, (unsigned)ns);
    }
  }
}

// ---------------- readout (col max + mean), 2-stage ----------------
__global__ void readout_part(const float* __restrict__ xs, int k, float* pmax, float* psum) {
  int h = threadIdx.x, b = blockIdx.x;
  float m = -INFINITY, s = 0.f;
  for (int r = b; r < k; r += 32) {
    float vv = xs[(size_t)r * H + h];
    m = fmaxf(m, vv);
    s += vv;
  }
  pmax[b * H + h] = m;
  psum[b * H + h] = s;
}
__global__ void readout_fin(const float* pmax, const float* psum, float* racc, float invk) {
  int h = threadIdx.x;
  float m = -INFINITY, s = 0.f;
  for (int b = 0; b < 32; ++b) { m = fmaxf(m, pmax[b * H + h]); s += psum[b * H + h]; }
  racc[h] += m;
  racc[H + h] += s * invk;
}
__global__ void final_kernel(const float* racc, float* out) {
  int t = blockIdx.x * 256 + threadIdx.x;
  if (t < 512) out[t] = racc[t];
}

extern "C" void kernel_launch(void* const* d_in, const int* in_sizes, int n_in,
                              void* d_out, int out_size, void* d_ws, size_t ws_size,
                              hipStream_t stream) {
  const float* feat = (const float*)d_in[0];
  const float* W1 = (const float*)d_in[1];  const float* b1 = (const float*)d_in[2];
  const float* W2 = (const float*)d_in[3];  const float* b2 = (const float*)d_in[4];
  const float* W3 = (const float*)d_in[5];  const float* b3 = (const float*)d_in[6];
  const float* Wr1 = (const float*)d_in[7]; const float* br1 = (const float*)d_in[8]; const float* Ws1 = (const float*)d_in[9];
  const float* Wr2 = (const float*)d_in[10]; const float* br2 = (const float*)d_in[11]; const float* Ws2 = (const float*)d_in[12];
  const float* Wr3 = (const float*)d_in[13]; const float* br3 = (const float*)d_in[14]; const float* Ws3 = (const float*)d_in[15];
  float* out = (float*)d_out;

  char* w = (char*)d_ws;
  size_t o = 0;
  auto alloc = [&](size_t bytes) { size_t cur = o; o += (bytes + 255) & ~(size_t)255; return cur; };
  float* racc  = (float*)(w + alloc(512 * 4));
  unsigned* dmax = (unsigned*)(w + alloc(4));
  unsigned* ecnt = (unsigned*)(w + alloc(4 * 4));
  float* sq    = (float*)(w + alloc(N0 * 4));
  float* tmin  = (float*)(w + alloc(4096 * 4));
  float* dinv  = (float*)(w + alloc(N0 * 4));
  float* u     = (float*)(w + alloc(N0 * 4));
  float* v     = (float*)(w + alloc(N0 * 4));
  float* score = (float*)(w + alloc(N0 * 4));
  int* newid   = (int*)(w + alloc(N0 * 4));
  float* pmax  = (float*)(w + alloc(32 * H * 4));
  float* psum  = (float*)(w + alloc(32 * H * 4));
  uint2* edgesA = (uint2*)(w + alloc(CAP * 8));
  uint2* edgesB = (uint2*)(w + alloc(CAP * 8));
  ush* Wth1 = (ush*)(w + alloc(256 * KPAD * 2));
  ush* Wtm1 = (ush*)(w + alloc(256 * KPAD * 2));
  ush* Wth2 = (ush*)(w + alloc(256 * 256 * 2));
  ush* Wtm2 = (ush*)(w + alloc(256 * 256 * 2));
  ush* Wth3 = (ush*)(w + alloc(256 * 256 * 2));
  ush* Wtm3 = (ush*)(w + alloc(256 * 256 * 2));
  float* xW = (float*)(w + alloc((size_t)N0 * H * 4));
  float* tmp = (float*)(w + alloc((size_t)N0 * H * 4));
  float* yA = (float*)(w + alloc((size_t)N0 * H * 4));   // overlay: Xh
  float* yB = (float*)(w + alloc((size_t)N0 * H * 4));   // overlay: Xm

  ush* Xh = (ush*)yA;   // [4096][512] bf16 (dist + layer-1 GEMM lifetime)
  ush* Xm = (ush*)yB;
  // pooled split-bf16 in tmp's dead window [after relu_uv_L .. before gcn_base_{L+1}]
  ush* Yh = (ush*)tmp;
  ush* Ym = (ush*)((char*)tmp + 2097152);

  init_kernel<<<1, 512, 0, stream>>>(racc, dmax, ecnt);
  convsq_kernel<<<N0, 256, 0, stream>>>(feat, Xh, Xm, sq);
  wtconv_all_kernel<<<1024, 256, 0, stream>>>(W1, W2, W3, Wth1, Wtm1, Wth2, Wtm2, Wth3, Wtm3);
  distm_kernel<0><<<528, 512, 0, stream>>>(Xh, Xm, sq, tmin, dmax, edgesA, ecnt);
  distm_kernel<1><<<528, 512, 0, stream>>>(Xh, Xm, sq, tmin, dmax, edgesA, ecnt);

  // ---- layer 1: n=N0, edges=edgesA(ecnt0) -> pooled k=KP1, edgesB(ecnt1)
  degdinv_kernel<<<1, 1024, 0, stream>>>(edgesA, &ecnt[0], dinv, N0);
  xwm_kernel<<<dim3(2, N0 / 128), 256, 0, stream>>>(Xh, Xm, KPAD, Wth1, Wtm1, KPAD, xW, KPAD / 32);
  gcn_base_kernel<<<N0, 256, 0, stream>>>(xW, dinv, tmp);
  gcn_edge_kernel<<<256, 256, 0, stream>>>(edgesA, &ecnt[0], xW, dinv, tmp);
  relu_uv_kernel<<<N0, 256, 0, stream>>>(tmp, b1, Wr1, Ws1, yA, u, v);
  select_kernel<<<1, 1024, 0, stream>>>(edgesA, &ecnt[0], u, v, br1, score, N0, KP1, newid, &ecnt[1]);
  gather_kernel<<<N0, 256, 0, stream>>>(yA, newid, score, yB, Yh, Ym);
  filter_kernel<<<CAP / 256, 256, 0, stream>>>(edgesA, &ecnt[0], newid, edgesB, &ecnt[1]);
  readout_part<<<32, 256, 0, stream>>>(yB, KP1, pmax, psum);
  readout_fin<<<1, 256, 0, stream>>>(pmax, psum, racc, 1.f / KP1);

  // ---- layer 2: n=KP1, edges=edgesB(ecnt1) -> pooled k=KP2, edgesA(ecnt2)
  degdinv_kernel<<<1, 1024, 0, stream>>>(edgesB, &ecnt[1], dinv, KP1);
  xwm_kernel<<<dim3(2, KP1 / 128), 256, 0, stream>>>(Yh, Ym, H, Wth2, Wtm2, H, xW, H / 32);
  gcn_base_kernel<<<KP1, 256, 0, stream>>>(xW, dinv, tmp);
  gcn_edge_kernel<<<256, 256, 0, stream>>>(edgesB, &ecnt[1], xW, dinv, tmp);
  relu_uv_kernel<<<KP1, 256, 0, stream>>>(tmp, b2, Wr2, Ws2, yA, u, v);
  select_kernel<<<1, 1024, 0, stream>>>(edgesB, &ecnt[1], u, v, br2, score, KP1, KP2, newid, &ecnt[2]);
  gather_kernel<<<KP1, 256, 0, stream>>>(yA, newid, score, yB, Yh, Ym);
  filter_kernel<<<CAP / 256, 256, 0, stream>>>(edgesB, &ecnt[1], newid, edgesA, &ecnt[2]);
  readout_part<<<32, 256, 0, stream>>>(yB, KP2, pmax, psum);
  readout_fin<<<1, 256, 0, stream>>>(pmax, psum, racc, 1.f / KP2);

  // ---- layer 3: n=KP2, edges=edgesA(ecnt2) -> pooled k=KP3
  degdinv_kernel<<<1, 1024, 0, stream>>>(edgesA, &ecnt[2], dinv, KP2);
  xwm_kernel<<<dim3(2, KP2 / 128), 256, 0, stream>>>(Yh, Ym, H, Wth3, Wtm3, H, xW, H / 32);
  gcn_base_kernel<<<KP2, 256, 0, stream>>>(xW, dinv, tmp);
  gcn_edge_kernel<<<256, 256, 0, stream>>>(edgesA, &ecnt[2], xW, dinv, tmp);
  relu_uv_kernel<<<KP2, 256, 0, stream>>>(tmp, b3, Wr3, Ws3, yA, u, v);
  select_kernel<<<1, 1024, 0, stream>>>(edgesA, &ecnt[2], u, v, br3, score, KP2, KP3, newid, &ecnt[3]);
  gather_kernel<<<KP2, 256, 0, stream>>>(yA, newid, score, yB, Yh, Ym);
  readout_part<<<32, 256, 0, stream>>>(yB, KP3, pmax, psum);
  readout_fin<<<1, 256, 0, stream>>>(pmax, psum, racc, 1.f / KP3);

  final_kernel<<<2, 256, 0, stream>>>(racc, out);
}